// Round 1
// baseline (986.745 us; speedup 1.0000x reference)
//
#include <hip/hip_runtime.h>
#include <hip/hip_bf16.h>
#include <math.h>

#define T_SEQ   2048
#define DM      1024
#define KF      32
#define BATCH   16
#define CPDIM   528
#define MROWS   (BATCH * T_SEQ)   // 32768
#define NCHUNK  32                // chunks per batch along T
#define TCHUNK  64                // T per chunk

// ---------------------------------------------------------------------------
// Kernel 1: fold filters through pre_w.
// W[i*64+k] (i<1024): k<32 -> sum_s pre_w[s,i]*q_filters[s,k]
//                     k>=32 -> sum_s pre_w[s,i]*k_filters[s,k-32]
// bias64[k]: pre_b folded the same way.
// ---------------------------------------------------------------------------
__global__ __launch_bounds__(64) void k_fold(const float* __restrict__ pre_w,
                                             const float* __restrict__ pre_b,
                                             const float* __restrict__ qf,
                                             const float* __restrict__ kf,
                                             float* __restrict__ W,
                                             float* __restrict__ bias64) {
  const int i = blockIdx.x;      // 0..1023
  const int k = threadIdx.x;     // 0..63
  const float* f = (k < KF) ? qf : kf;
  const int kk = k & (KF - 1);
  float acc = 0.f;
  for (int s = 0; s < T_SEQ; ++s)
    acc = fmaf(pre_w[(size_t)s * DM + i], f[s * KF + kk], acc);
  W[i * 64 + k] = acc;
  if (i == 0) {
    float b = 0.f;
    for (int s = 0; s < T_SEQ; ++s)
      b = fmaf(pre_b[s], f[s * KF + kk], b);
    bias64[k] = b;
  }
}

// ---------------------------------------------------------------------------
// Kernel 2: Q0V = x @ W + bias64.  M=32768, K=1024, N=64.
// 64x64 tile per block, 256 threads, 4x4 per thread.
// ---------------------------------------------------------------------------
__global__ __launch_bounds__(256) void k_q0v(const float* __restrict__ x,
                                             const float* __restrict__ W,
                                             const float* __restrict__ bias64,
                                             float* __restrict__ Q0V) {
  __shared__ float xs[64][65];
  __shared__ float ws[64][65];
  const int m0 = blockIdx.x * 64;
  const int tid = threadIdx.x;
  const int tr = tid >> 4;       // 0..15 -> rows tr*4..tr*4+3
  const int tc = tid & 15;       // 0..15 -> cols tc*4..tc*4+3
  float acc[4][4] = {};

  for (int k0 = 0; k0 < DM; k0 += 64) {
#pragma unroll
    for (int i = 0; i < 4; ++i) {
      const int r = (tid >> 4) + i * 16;
      const int c = (tid & 15) * 4;
      const float4 a = *reinterpret_cast<const float4*>(&x[(size_t)(m0 + r) * DM + k0 + c]);
      xs[r][c] = a.x; xs[r][c + 1] = a.y; xs[r][c + 2] = a.z; xs[r][c + 3] = a.w;
      const float4 b = *reinterpret_cast<const float4*>(&W[(size_t)(k0 + r) * 64 + c]);
      ws[r][c] = b.x; ws[r][c + 1] = b.y; ws[r][c + 2] = b.z; ws[r][c + 3] = b.w;
    }
    __syncthreads();
#pragma unroll
    for (int kk = 0; kk < 64; ++kk) {
      float a[4], b[4];
#pragma unroll
      for (int r = 0; r < 4; ++r) a[r] = xs[tr * 4 + r][kk];
#pragma unroll
      for (int c = 0; c < 4; ++c) b[c] = ws[kk][tc * 4 + c];
#pragma unroll
      for (int r = 0; r < 4; ++r)
#pragma unroll
        for (int c = 0; c < 4; ++c)
          acc[r][c] = fmaf(a[r], b[c], acc[r][c]);
    }
    __syncthreads();
  }
#pragma unroll
  for (int r = 0; r < 4; ++r)
#pragma unroll
    for (int c = 0; c < 4; ++c)
      Q0V[(size_t)(m0 + tr * 4 + r) * 64 + tc * 4 + c] = acc[r][c] + bias64[tc * 4 + c];
}

// ---------------------------------------------------------------------------
// Kernel 3: per-chunk sums of Z.  S[(b*32+ch)*528+c] = sum over chunk of z.
// ---------------------------------------------------------------------------
__global__ __launch_bounds__(576) void k_chunksum(const float* __restrict__ Q0V,
                                                  const float* __restrict__ decay,
                                                  float* __restrict__ S) {
  const int ch = blockIdx.x;   // 0..31
  const int b  = blockIdx.y;   // 0..15
  __shared__ float vs[TCHUNK * KF];
  __shared__ float dec[TCHUNK];
  const int tid = threadIdx.x;
  const int t0 = ch * TCHUNK;

  for (int idx = tid; idx < TCHUNK * KF; idx += 576) {
    const int t = idx >> 5, j = idx & 31;
    vs[idx] = Q0V[(size_t)(b * T_SEQ + t0 + t) * 64 + KF + j];
  }
  if (tid < TCHUNK) dec[tid] = decay[t0 + tid];
  __syncthreads();

  if (tid >= CPDIM) return;
  const int c = tid;
  int i = 0, rem = c;
  while (rem >= KF - i) { rem -= KF - i; ++i; }
  const int j = i + rem;
  const float sc = (i == j) ? 1.0f : 1.41421356237309515f;
  float h = 0.f;
#pragma unroll 4
  for (int t = 0; t < TCHUNK; ++t)
    h = fmaf(vs[t * KF + i] * vs[t * KF + j], dec[t], h);
  S[(size_t)(b * NCHUNK + ch) * CPDIM + c] = h * sc;
}

// ---------------------------------------------------------------------------
// Kernel 4: exclusive scan of chunk sums over the 32 chunks (in place).
// ---------------------------------------------------------------------------
__global__ __launch_bounds__(576) void k_scanchunks(float* __restrict__ S) {
  const int b = blockIdx.x;
  const int c = threadIdx.x;
  if (c >= CPDIM) return;
  float run = 0.f;
  for (int ch = 0; ch < NCHUNK; ++ch) {
    const size_t idx = (size_t)(b * NCHUNK + ch) * CPDIM + c;
    const float v = S[idx];
    S[idx] = run;
    run += v;
  }
}

// ---------------------------------------------------------------------------
// Kernel 5: replay scan with offsets, expand Q through qp_w, write Y = Q*H.
// ---------------------------------------------------------------------------
__global__ __launch_bounds__(576) void k_scan_y(const float* __restrict__ Q0V,
                                                const float* __restrict__ S,
                                                const float* __restrict__ qp_w,
                                                const float* __restrict__ qp_b,
                                                const float* __restrict__ decay,
                                                float* __restrict__ Y) {
  const int ch = blockIdx.x;   // 0..31
  const int b  = blockIdx.y;   // 0..15
  __shared__ float vs[TCHUNK * KF];
  __shared__ float qs[TCHUNK * KF];
  __shared__ float dec[TCHUNK];
  const int tid = threadIdx.x;
  const int t0 = ch * TCHUNK;

  for (int idx = tid; idx < TCHUNK * KF; idx += 576) {
    const int t = idx >> 5, j = idx & 31;
    const size_t row = (size_t)(b * T_SEQ + t0 + t) * 64;
    qs[idx] = Q0V[row + j];
    vs[idx] = Q0V[row + KF + j];
  }
  if (tid < TCHUNK) dec[tid] = decay[t0 + tid];
  __syncthreads();

  if (tid >= CPDIM) return;
  const int c = tid;
  int i = 0, rem = c;
  while (rem >= KF - i) { rem -= KF - i; ++i; }
  const int j = i + rem;
  const float sc = (i == j) ? 1.0f : 1.41421356237309515f;

  float w[KF];
#pragma unroll
  for (int q = 0; q < KF; ++q) w[q] = qp_w[c * KF + q];
  const float qb = qp_b[c];

  float h = S[(size_t)(b * NCHUNK + ch) * CPDIM + c];
  for (int t = 0; t < TCHUNK; ++t) {
    const float z = vs[t * KF + i] * vs[t * KF + j] * sc * dec[t];
    h += z;
    float qv = qb;
#pragma unroll
    for (int q = 0; q < KF; ++q) qv = fmaf(w[q], qs[t * KF + q], qv);
    Y[(size_t)(b * T_SEQ + t0 + t) * CPDIM + c] = qv * h;
  }
}

// ---------------------------------------------------------------------------
// Kernel 6: out = Y @ o_w^T + o_b.  M=32768, N=1024, K=528.
// 128x128 tile, 256 threads, 8x8 per thread, BK=16.
// ---------------------------------------------------------------------------
__global__ __launch_bounds__(256) void k_out(const float* __restrict__ Y,
                                             const float* __restrict__ ow,
                                             const float* __restrict__ ob,
                                             float* __restrict__ out) {
  __shared__ float ys[128][17];
  __shared__ float ws[128][17];
  const int m0 = blockIdx.x * 128;   // 256 blocks
  const int n0 = blockIdx.y * 128;   // 8 blocks
  const int tid = threadIdx.x;
  const int tr = tid >> 4;           // rows tr*8..tr*8+7
  const int tc = tid & 15;           // cols tc*8..tc*8+7
  float acc[8][8] = {};

  for (int k0 = 0; k0 < CPDIM; k0 += 16) {
    const int r = tid >> 2;          // 0..63
    const int c4 = (tid & 3) * 4;    // 0,4,8,12
#pragma unroll
    for (int h = 0; h < 2; ++h) {
      const float4 a = *reinterpret_cast<const float4*>(&Y[(size_t)(m0 + r + h * 64) * CPDIM + k0 + c4]);
      ys[r + h * 64][c4] = a.x; ys[r + h * 64][c4 + 1] = a.y;
      ys[r + h * 64][c4 + 2] = a.z; ys[r + h * 64][c4 + 3] = a.w;
      const float4 bq = *reinterpret_cast<const float4*>(&ow[(size_t)(n0 + r + h * 64) * CPDIM + k0 + c4]);
      ws[r + h * 64][c4] = bq.x; ws[r + h * 64][c4 + 1] = bq.y;
      ws[r + h * 64][c4 + 2] = bq.z; ws[r + h * 64][c4 + 3] = bq.w;
    }
    __syncthreads();
#pragma unroll
    for (int kk = 0; kk < 16; ++kk) {
      float a[8], bb[8];
#pragma unroll
      for (int r8 = 0; r8 < 8; ++r8) a[r8] = ys[tr * 8 + r8][kk];
#pragma unroll
      for (int c8 = 0; c8 < 8; ++c8) bb[c8] = ws[tc * 8 + c8][kk];
#pragma unroll
      for (int r8 = 0; r8 < 8; ++r8)
#pragma unroll
        for (int c8 = 0; c8 < 8; ++c8)
          acc[r8][c8] = fmaf(a[r8], bb[c8], acc[r8][c8]);
    }
    __syncthreads();
  }

#pragma unroll
  for (int r8 = 0; r8 < 8; ++r8) {
    const size_t row = (size_t)(m0 + tr * 8 + r8) * DM + n0 + tc * 8;
#pragma unroll
    for (int c8 = 0; c8 < 8; c8 += 4) {
      float4 v;
      v.x = acc[r8][c8]     + ob[n0 + tc * 8 + c8];
      v.y = acc[r8][c8 + 1] + ob[n0 + tc * 8 + c8 + 1];
      v.z = acc[r8][c8 + 2] + ob[n0 + tc * 8 + c8 + 2];
      v.w = acc[r8][c8 + 3] + ob[n0 + tc * 8 + c8 + 3];
      *reinterpret_cast<float4*>(&out[row + c8]) = v;
    }
  }
}

// ---------------------------------------------------------------------------
extern "C" void kernel_launch(void* const* d_in, const int* in_sizes, int n_in,
                              void* d_out, int out_size, void* d_ws, size_t ws_size,
                              hipStream_t stream) {
  const float* x      = (const float*)d_in[0];
  const float* pre_w  = (const float*)d_in[1];
  const float* pre_b  = (const float*)d_in[2];
  const float* q_filt = (const float*)d_in[3];
  const float* k_filt = (const float*)d_in[4];
  const float* qp_w   = (const float*)d_in[5];
  const float* qp_b   = (const float*)d_in[6];
  const float* o_w    = (const float*)d_in[7];
  const float* o_b    = (const float*)d_in[8];
  const float* decay  = (const float*)d_in[9];
  float* out = (float*)d_out;

  char* ws = (char*)d_ws;
  float* W      = (float*)(ws);                       // 1024*64 = 256 KB
  float* bias64 = (float*)(ws + 262144);              // 64 floats
  float* Q0V    = (float*)(ws + 262400);              // 32768*64*4 = 8.39 MB
  float* S      = (float*)(ws + 8651008);             // 16*32*528*4 = 1.08 MB
  float* Y      = (float*)(ws + 9732352);             // 32768*528*4 = 69.2 MB
  // total ~78.9 MB

  k_fold<<<dim3(DM), dim3(64), 0, stream>>>(pre_w, pre_b, q_filt, k_filt, W, bias64);
  k_q0v<<<dim3(MROWS / 64), dim3(256), 0, stream>>>(x, W, bias64, Q0V);
  k_chunksum<<<dim3(NCHUNK, BATCH), dim3(576), 0, stream>>>(Q0V, decay, S);
  k_scanchunks<<<dim3(BATCH), dim3(576), 0, stream>>>(S);
  k_scan_y<<<dim3(NCHUNK, BATCH), dim3(576), 0, stream>>>(Q0V, S, qp_w, qp_b, decay, Y);
  k_out<<<dim3(MROWS / 128, DM / 128), dim3(256), 0, stream>>>(Y, o_w, o_b, out);
}

// Round 2
// 536.866 us; speedup vs baseline: 1.8380x; 1.8380x over previous
//
#include <hip/hip_runtime.h>
#include <hip/hip_bf16.h>
#include <math.h>

#define T_SEQ   2048
#define DM      1024
#define KF      32
#define BATCH   16
#define CPDIM   528
#define MROWS   (BATCH * T_SEQ)   // 32768
#define NCHUNK  32                // chunks per batch along T
#define TCHUNK  64                // T per chunk

typedef __bf16 bf16x8 __attribute__((ext_vector_type(8)));
typedef float f32x4 __attribute__((ext_vector_type(4)));
typedef unsigned short ushort8v __attribute__((ext_vector_type(8)));

__device__ __forceinline__ unsigned short f2bf(float f) {
  unsigned u = __float_as_uint(f);
  return (unsigned short)((u + 0x7fffu + ((u >> 16) & 1u)) >> 16);  // RNE
}
__device__ __forceinline__ float bf2f(unsigned short h) {
  return __uint_as_float((unsigned)h << 16);
}

// ---------------------------------------------------------------------------
// Kernel 1: fold filters through pre_w.
// ---------------------------------------------------------------------------
__global__ __launch_bounds__(64) void k_fold(const float* __restrict__ pre_w,
                                             const float* __restrict__ pre_b,
                                             const float* __restrict__ qf,
                                             const float* __restrict__ kf,
                                             float* __restrict__ W,
                                             float* __restrict__ bias64) {
  const int i = blockIdx.x;      // 0..1023
  const int k = threadIdx.x;     // 0..63
  const float* f = (k < KF) ? qf : kf;
  const int kk = k & (KF - 1);
  float acc = 0.f;
  for (int s = 0; s < T_SEQ; ++s)
    acc = fmaf(pre_w[(size_t)s * DM + i], f[s * KF + kk], acc);
  W[i * 64 + k] = acc;
  if (i == 0) {
    float b = 0.f;
    for (int s = 0; s < T_SEQ; ++s)
      b = fmaf(pre_b[s], f[s * KF + kk], b);
    bias64[k] = b;
  }
}

// ---------------------------------------------------------------------------
// Kernel 2: Q0V = x @ W + bias64.  M=32768, K=1024, N=64.
// ---------------------------------------------------------------------------
__global__ __launch_bounds__(256) void k_q0v(const float* __restrict__ x,
                                             const float* __restrict__ W,
                                             const float* __restrict__ bias64,
                                             float* __restrict__ Q0V) {
  __shared__ float xs[64][65];
  __shared__ float ws[64][65];
  const int m0 = blockIdx.x * 64;
  const int tid = threadIdx.x;
  const int tr = tid >> 4;
  const int tc = tid & 15;
  float acc[4][4] = {};

  for (int k0 = 0; k0 < DM; k0 += 64) {
#pragma unroll
    for (int i = 0; i < 4; ++i) {
      const int r = (tid >> 4) + i * 16;
      const int c = (tid & 15) * 4;
      const float4 a = *reinterpret_cast<const float4*>(&x[(size_t)(m0 + r) * DM + k0 + c]);
      xs[r][c] = a.x; xs[r][c + 1] = a.y; xs[r][c + 2] = a.z; xs[r][c + 3] = a.w;
      const float4 b = *reinterpret_cast<const float4*>(&W[(size_t)(k0 + r) * 64 + c]);
      ws[r][c] = b.x; ws[r][c + 1] = b.y; ws[r][c + 2] = b.z; ws[r][c + 3] = b.w;
    }
    __syncthreads();
#pragma unroll
    for (int kk = 0; kk < 64; ++kk) {
      float a[4], b[4];
#pragma unroll
      for (int r = 0; r < 4; ++r) a[r] = xs[tr * 4 + r][kk];
#pragma unroll
      for (int c = 0; c < 4; ++c) b[c] = ws[kk][tc * 4 + c];
#pragma unroll
      for (int r = 0; r < 4; ++r)
#pragma unroll
        for (int c = 0; c < 4; ++c)
          acc[r][c] = fmaf(a[r], b[c], acc[r][c]);
    }
    __syncthreads();
  }
#pragma unroll
  for (int r = 0; r < 4; ++r)
#pragma unroll
    for (int c = 0; c < 4; ++c)
      Q0V[(size_t)(m0 + tr * 4 + r) * 64 + tc * 4 + c] = acc[r][c] + bias64[tc * 4 + c];
}

// ---------------------------------------------------------------------------
// Kernel 3: per-chunk sums of Z.
// ---------------------------------------------------------------------------
__global__ __launch_bounds__(576) void k_chunksum(const float* __restrict__ Q0V,
                                                  const float* __restrict__ decay,
                                                  float* __restrict__ S) {
  const int ch = blockIdx.x;
  const int b  = blockIdx.y;
  __shared__ float vs[TCHUNK * KF];
  __shared__ float dec[TCHUNK];
  const int tid = threadIdx.x;
  const int t0 = ch * TCHUNK;

  for (int idx = tid; idx < TCHUNK * KF; idx += 576) {
    const int t = idx >> 5, j = idx & 31;
    vs[idx] = Q0V[(size_t)(b * T_SEQ + t0 + t) * 64 + KF + j];
  }
  if (tid < TCHUNK) dec[tid] = decay[t0 + tid];
  __syncthreads();

  if (tid >= CPDIM) return;
  const int c = tid;
  int i = 0, rem = c;
  while (rem >= KF - i) { rem -= KF - i; ++i; }
  const int j = i + rem;
  const float sc = (i == j) ? 1.0f : 1.41421356237309515f;
  float h = 0.f;
#pragma unroll 4
  for (int t = 0; t < TCHUNK; ++t)
    h = fmaf(vs[t * KF + i] * vs[t * KF + j], dec[t], h);
  S[(size_t)(b * NCHUNK + ch) * CPDIM + c] = h * sc;
}

// ---------------------------------------------------------------------------
// Kernel 4: exclusive scan of chunk sums (in place).
// ---------------------------------------------------------------------------
__global__ __launch_bounds__(576) void k_scanchunks(float* __restrict__ S) {
  const int b = blockIdx.x;
  const int c = threadIdx.x;
  if (c >= CPDIM) return;
  float run = 0.f;
  for (int ch = 0; ch < NCHUNK; ++ch) {
    const size_t idx = (size_t)(b * NCHUNK + ch) * CPDIM + c;
    const float v = S[idx];
    S[idx] = run;
    run += v;
  }
}

// ---------------------------------------------------------------------------
// Kernel 5: replay scan with offsets, expand Q, write Y = Q*H (fp32).
// ---------------------------------------------------------------------------
__global__ __launch_bounds__(576) void k_scan_y(const float* __restrict__ Q0V,
                                                const float* __restrict__ S,
                                                const float* __restrict__ qp_w,
                                                const float* __restrict__ qp_b,
                                                const float* __restrict__ decay,
                                                float* __restrict__ Y) {
  const int ch = blockIdx.x;
  const int b  = blockIdx.y;
  __shared__ float vs[TCHUNK * KF];
  __shared__ float qs[TCHUNK * KF];
  __shared__ float dec[TCHUNK];
  const int tid = threadIdx.x;
  const int t0 = ch * TCHUNK;

  for (int idx = tid; idx < TCHUNK * KF; idx += 576) {
    const int t = idx >> 5, j = idx & 31;
    const size_t row = (size_t)(b * T_SEQ + t0 + t) * 64;
    qs[idx] = Q0V[row + j];
    vs[idx] = Q0V[row + KF + j];
  }
  if (tid < TCHUNK) dec[tid] = decay[t0 + tid];
  __syncthreads();

  if (tid >= CPDIM) return;
  const int c = tid;
  int i = 0, rem = c;
  while (rem >= KF - i) { rem -= KF - i; ++i; }
  const int j = i + rem;
  const float sc = (i == j) ? 1.0f : 1.41421356237309515f;

  float w[KF];
#pragma unroll
  for (int q = 0; q < KF; ++q) w[q] = qp_w[c * KF + q];
  const float qb = qp_b[c];

  float h = S[(size_t)(b * NCHUNK + ch) * CPDIM + c];
  for (int t = 0; t < TCHUNK; ++t) {
    const float z = vs[t * KF + i] * vs[t * KF + j] * sc * dec[t];
    h += z;
    float qv = qb;
#pragma unroll
    for (int q = 0; q < KF; ++q) qv = fmaf(w[q], qs[t * KF + q], qv);
    Y[(size_t)(b * T_SEQ + t0 + t) * CPDIM + c] = qv * h;
  }
}

// ---------------------------------------------------------------------------
// Kernel 6: out = Y @ o_w^T + o_b via bf16 split-MFMA (3-term emulation).
// M=32768, N=1024, K=528. 128x128 tile, BK=32, 4 waves.
// LDS tiles padded to stride 40 halves -> frag ds_read_b128 is 2-way (free).
// ---------------------------------------------------------------------------
__global__ __launch_bounds__(256) void k_out_mfma(const float* __restrict__ Y,
                                                  const float* __restrict__ ow,
                                                  const float* __restrict__ ob,
                                                  float* __restrict__ out) {
  __shared__ unsigned short Ahi[128 * 40];
  __shared__ unsigned short Alo[128 * 40];
  __shared__ unsigned short Bhi[128 * 40];
  __shared__ unsigned short Blo[128 * 40];

  const int tid = threadIdx.x;
  const int n0 = blockIdx.x * 128;   // 8 n-blocks (fast) -> Y panel L2 reuse
  const int m0 = blockIdx.y * 128;   // 256 m-blocks
  const int w  = tid >> 6;
  const int l  = tid & 63;
  const int wr = w >> 1, wc = w & 1;       // 2x2 waves, each 64x64
  const int g  = l >> 4, r = l & 15;
  const int srow = tid >> 1;               // staging: row 0..127
  const int c0   = (tid & 1) * 16;         // staging: col half 0 / 16

  f32x4 acc[4][4] = {};

  for (int k0 = 0; k0 < CPDIM; k0 += 32) {
    // ---- global loads (f32) ----
    float va[16], vb[16];
#pragma unroll
    for (int q = 0; q < 4; ++q) {
      const int col = k0 + c0 + q * 4;
      float4 fa, fb;
      if (col < CPDIM) {
        fa = *reinterpret_cast<const float4*>(&Y [(size_t)(m0 + srow) * CPDIM + col]);
        fb = *reinterpret_cast<const float4*>(&ow[(size_t)(n0 + srow) * CPDIM + col]);
      } else {
        fa = make_float4(0.f, 0.f, 0.f, 0.f);
        fb = make_float4(0.f, 0.f, 0.f, 0.f);
      }
      va[q * 4 + 0] = fa.x; va[q * 4 + 1] = fa.y; va[q * 4 + 2] = fa.z; va[q * 4 + 3] = fa.w;
      vb[q * 4 + 0] = fb.x; vb[q * 4 + 1] = fb.y; vb[q * 4 + 2] = fb.z; vb[q * 4 + 3] = fb.w;
    }

    __syncthreads();   // previous iteration's frag reads complete

    // ---- split to hi/lo bf16, write LDS ----
#pragma unroll
    for (int hb = 0; hb < 2; ++hb) {
      ushort8v ah, al, bh, bl;
#pragma unroll
      for (int e = 0; e < 8; ++e) {
        float v = va[hb * 8 + e];
        unsigned short h = f2bf(v);
        ah[e] = h; al[e] = f2bf(v - bf2f(h));
        v = vb[hb * 8 + e];
        h = f2bf(v);
        bh[e] = h; bl[e] = f2bf(v - bf2f(h));
      }
      const int off = srow * 40 + c0 + hb * 8;
      *reinterpret_cast<ushort8v*>(&Ahi[off]) = ah;
      *reinterpret_cast<ushort8v*>(&Alo[off]) = al;
      *reinterpret_cast<ushort8v*>(&Bhi[off]) = bh;
      *reinterpret_cast<ushort8v*>(&Blo[off]) = bl;
    }

    __syncthreads();

    // ---- load fragments ----
    bf16x8 fah[4], fal[4], fbh[4], fbl[4];
#pragma unroll
    for (int m = 0; m < 4; ++m) {
      const int off = (wr * 64 + m * 16 + r) * 40 + g * 8;
      fah[m] = *reinterpret_cast<const bf16x8*>(&Ahi[off]);
      fal[m] = *reinterpret_cast<const bf16x8*>(&Alo[off]);
    }
#pragma unroll
    for (int n = 0; n < 4; ++n) {
      const int off = (wc * 64 + n * 16 + r) * 40 + g * 8;
      fbh[n] = *reinterpret_cast<const bf16x8*>(&Bhi[off]);
      fbl[n] = *reinterpret_cast<const bf16x8*>(&Blo[off]);
    }

    // ---- 3-term split MFMA, shared accumulator ----
#pragma unroll
    for (int m = 0; m < 4; ++m)
#pragma unroll
      for (int n = 0; n < 4; ++n) {
        acc[m][n] = __builtin_amdgcn_mfma_f32_16x16x32_bf16(fah[m], fbh[n], acc[m][n], 0, 0, 0);
        acc[m][n] = __builtin_amdgcn_mfma_f32_16x16x32_bf16(fah[m], fbl[n], acc[m][n], 0, 0, 0);
        acc[m][n] = __builtin_amdgcn_mfma_f32_16x16x32_bf16(fal[m], fbh[n], acc[m][n], 0, 0, 0);
      }
  }

  // ---- epilogue: C layout col=lane&15, row=(lane>>4)*4+j ----
#pragma unroll
  for (int m = 0; m < 4; ++m) {
    const int row = m0 + wr * 64 + m * 16 + g * 4;
#pragma unroll
    for (int n = 0; n < 4; ++n) {
      const int col = n0 + wc * 64 + n * 16 + r;
      const float bias = ob[col];
#pragma unroll
      for (int j = 0; j < 4; ++j)
        out[(size_t)(row + j) * DM + col] = acc[m][n][j] + bias;
    }
  }
}

// ---------------------------------------------------------------------------
extern "C" void kernel_launch(void* const* d_in, const int* in_sizes, int n_in,
                              void* d_out, int out_size, void* d_ws, size_t ws_size,
                              hipStream_t stream) {
  const float* x      = (const float*)d_in[0];
  const float* pre_w  = (const float*)d_in[1];
  const float* pre_b  = (const float*)d_in[2];
  const float* q_filt = (const float*)d_in[3];
  const float* k_filt = (const float*)d_in[4];
  const float* qp_w   = (const float*)d_in[5];
  const float* qp_b   = (const float*)d_in[6];
  const float* o_w    = (const float*)d_in[7];
  const float* o_b    = (const float*)d_in[8];
  const float* decay  = (const float*)d_in[9];
  float* out = (float*)d_out;

  char* ws = (char*)d_ws;
  float* W      = (float*)(ws);                       // 256 KB
  float* bias64 = (float*)(ws + 262144);              // 64 floats
  float* Q0V    = (float*)(ws + 262400);              // 8.39 MB
  float* S      = (float*)(ws + 8651008);             // 1.08 MB
  float* Y      = (float*)(ws + 9732352);             // 69.2 MB
  // total ~78.9 MB (unchanged from round 0)

  k_fold<<<dim3(DM), dim3(64), 0, stream>>>(pre_w, pre_b, q_filt, k_filt, W, bias64);
  k_q0v<<<dim3(MROWS / 64), dim3(256), 0, stream>>>(x, W, bias64, Q0V);
  k_chunksum<<<dim3(NCHUNK, BATCH), dim3(576), 0, stream>>>(Q0V, decay, S);
  k_scanchunks<<<dim3(BATCH), dim3(576), 0, stream>>>(S);
  k_scan_y<<<dim3(NCHUNK, BATCH), dim3(576), 0, stream>>>(Q0V, S, qp_w, qp_b, decay, Y);
  k_out_mfma<<<dim3(DM / 128, MROWS / 128), dim3(256), 0, stream>>>(Y, o_w, o_b, out);
}

// Round 3
// 359.140 us; speedup vs baseline: 2.7475x; 1.4949x over previous
//
#include <hip/hip_runtime.h>
#include <hip/hip_bf16.h>
#include <math.h>

#define T_SEQ   2048
#define DM      1024
#define KF      32
#define BATCH   16
#define CPDIM   528
#define MROWS   (BATCH * T_SEQ)   // 32768
#define NCHUNK  32
#define TCHUNK  64

typedef __bf16 bf16x8 __attribute__((ext_vector_type(8)));
typedef float f32x4 __attribute__((ext_vector_type(4)));
typedef unsigned uint2v __attribute__((ext_vector_type(2)));

// split v into bf16 hi (RNE) + bf16 lo (trunc of residual), packed (hi<<16)|lo
__device__ __forceinline__ unsigned packsplit(float v) {
  unsigned u = __float_as_uint(v);
  unsigned h = (u + 0x7fffu + ((u >> 16) & 1u)) & 0xffff0000u;
  float rr = v - __uint_as_float(h);
  return h | (__float_as_uint(rr) >> 16);
}

// 4 packed u32 -> 4 hi halves + 4 lo halves (k-ascending), stored as 8B each
__device__ __forceinline__ void unpack_store(uint4 q, unsigned short* hi, unsigned short* lo) {
  unsigned hi01 = (q.x >> 16) | (q.y & 0xffff0000u);
  unsigned hi23 = (q.z >> 16) | (q.w & 0xffff0000u);
  unsigned lo01 = (q.x & 0xffffu) | (q.y << 16);
  unsigned lo23 = (q.z & 0xffffu) | (q.w << 16);
  uint2v h2 = {hi01, hi23};
  uint2v l2 = {lo01, lo23};
  *reinterpret_cast<uint2v*>(hi) = h2;
  *reinterpret_cast<uint2v*>(lo) = l2;
}

// ---------------------------------------------------------------------------
// Kernel 1: fold filters through pre_w -> Wt hi/lo bf16, transposed [64][1024].
// Wt[k][i] = sum_s pre_w[s,i] * f[s,k]   (k<32: q_filters, k>=32: k_filters)
// 256 blocks x 4 i-values, 256 threads (k = tid&63, iq = tid>>6).
// ---------------------------------------------------------------------------
__global__ __launch_bounds__(256) void k_fold(const float* __restrict__ pre_w,
                                              const float* __restrict__ qf,
                                              const float* __restrict__ kfil,
                                              unsigned short* __restrict__ Wt_hi,
                                              unsigned short* __restrict__ Wt_lo) {
  const int i0 = blockIdx.x * 4;
  const int tid = threadIdx.x;
  const int k = tid & 63;
  const int iq = tid >> 6;
  const int i = i0 + iq;
  __shared__ float fs[64][64];
  __shared__ float ps[64][4];
  float acc = 0.f;
  for (int s0 = 0; s0 < T_SEQ; s0 += 64) {
    __syncthreads();
    for (int idx = tid; idx < 64 * 64; idx += 256) {
      const int s = idx >> 6, kk = idx & 63;
      fs[s][kk] = (kk < KF) ? qf[(s0 + s) * KF + kk] : kfil[(s0 + s) * KF + kk - KF];
    }
    {
      const int s = tid >> 2, ii = tid & 3;
      ps[s][ii] = pre_w[(size_t)(s0 + s) * DM + i0 + ii];
    }
    __syncthreads();
#pragma unroll 8
    for (int s = 0; s < 64; ++s)
      acc = fmaf(ps[s][iq], fs[s][k], acc);
  }
  const unsigned pk = packsplit(acc);
  Wt_hi[(size_t)k * DM + i] = (unsigned short)(pk >> 16);
  Wt_lo[(size_t)k * DM + i] = (unsigned short)(pk & 0xffffu);
}

// ---------------------------------------------------------------------------
// Kernel 1b: bias64[k] = sum_s pre_b[s] * f[s,k]. One block, 4 partials/k.
// ---------------------------------------------------------------------------
__global__ __launch_bounds__(256) void k_bias(const float* __restrict__ pre_b,
                                              const float* __restrict__ qf,
                                              const float* __restrict__ kfil,
                                              float* __restrict__ bias64) {
  __shared__ float part[4][64];
  const int k = threadIdx.x & 63;
  const int q = threadIdx.x >> 6;
  float acc = 0.f;
  for (int s = q * 512; s < (q + 1) * 512; ++s) {
    const float fv = (k < KF) ? qf[s * KF + k] : kfil[s * KF + k - KF];
    acc = fmaf(pre_b[s], fv, acc);
  }
  part[q][k] = acc;
  __syncthreads();
  if (threadIdx.x < 64)
    bias64[threadIdx.x] = part[0][k] + part[1][k] + part[2][k] + part[3][k];
}

// ---------------------------------------------------------------------------
// Kernel 2: Q0V = x @ Wt^T + bias64 via 3-term bf16 split MFMA.
// M=32768, N=64, K=1024. 256 blocks x 128 rows, 512 threads (8 waves x 16 rows).
// B frags read directly from L2-resident Wt hi/lo.
// ---------------------------------------------------------------------------
__global__ __launch_bounds__(512) void k_q0v(const float* __restrict__ x,
                                             const unsigned short* __restrict__ Wt_hi,
                                             const unsigned short* __restrict__ Wt_lo,
                                             const float* __restrict__ bias64,
                                             float* __restrict__ Q0V) {
  __shared__ unsigned short Ahi[128 * 40];
  __shared__ unsigned short Alo[128 * 40];
  const int tid = threadIdx.x;
  const int m0 = blockIdx.x * 128;
  const int w = tid >> 6;            // wave -> rows w*16..+15
  const int l = tid & 63;
  const int g = l >> 4, r = l & 15;
  const int lrow = tid >> 3;         // 0..63
  const int lq = tid & 7;            // 4 floats each

  f32x4 acc[4] = {};

  float4 fa[2];
#pragma unroll
  for (int r4 = 0; r4 < 2; ++r4)
    fa[r4] = *reinterpret_cast<const float4*>(&x[(size_t)(m0 + lrow + r4 * 64) * DM + lq * 4]);

  for (int k0 = 0; k0 < DM; k0 += 32) {
    __syncthreads();
#pragma unroll
    for (int r4 = 0; r4 < 2; ++r4) {
      const unsigned p0 = packsplit(fa[r4].x);
      const unsigned p1 = packsplit(fa[r4].y);
      const unsigned p2 = packsplit(fa[r4].z);
      const unsigned p3 = packsplit(fa[r4].w);
      uint2v h2 = {(p0 >> 16) | (p1 & 0xffff0000u), (p2 >> 16) | (p3 & 0xffff0000u)};
      uint2v l2 = {(p0 & 0xffffu) | (p1 << 16),     (p2 & 0xffffu) | (p3 << 16)};
      const int off = (lrow + r4 * 64) * 40 + lq * 4;
      *reinterpret_cast<uint2v*>(&Ahi[off]) = h2;
      *reinterpret_cast<uint2v*>(&Alo[off]) = l2;
    }
    if (k0 + 32 < DM) {
#pragma unroll
      for (int r4 = 0; r4 < 2; ++r4)
        fa[r4] = *reinterpret_cast<const float4*>(&x[(size_t)(m0 + lrow + r4 * 64) * DM + k0 + 32 + lq * 4]);
    }
    // B fragments for current k0 (L2-resident, no LDS)
    bf16x8 bh[4], bl[4];
#pragma unroll
    for (int n = 0; n < 4; ++n) {
      const size_t boff = (size_t)(n * 16 + r) * DM + k0 + g * 8;
      bh[n] = *reinterpret_cast<const bf16x8*>(&Wt_hi[boff]);
      bl[n] = *reinterpret_cast<const bf16x8*>(&Wt_lo[boff]);
    }
    __syncthreads();
    const int aoff = (w * 16 + r) * 40 + g * 8;
    const bf16x8 ah = *reinterpret_cast<const bf16x8*>(&Ahi[aoff]);
    const bf16x8 al = *reinterpret_cast<const bf16x8*>(&Alo[aoff]);
#pragma unroll
    for (int n = 0; n < 4; ++n) {
      acc[n] = __builtin_amdgcn_mfma_f32_16x16x32_bf16(bh[n], ah, acc[n], 0, 0, 0);
      acc[n] = __builtin_amdgcn_mfma_f32_16x16x32_bf16(bh[n], al, acc[n], 0, 0, 0);
      acc[n] = __builtin_amdgcn_mfma_f32_16x16x32_bf16(bl[n], ah, acc[n], 0, 0, 0);
    }
  }
  // D: row-idx(g*4+j) <-> first operand (W, Q0V col), col-idx(r) <-> second (x, Q0V row)
  const int row_o = m0 + w * 16 + r;
#pragma unroll
  for (int n = 0; n < 4; ++n) {
    const int col_o = n * 16 + g * 4;
    const float4 bb = *reinterpret_cast<const float4*>(&bias64[col_o]);
    float4 v;
    v.x = acc[n][0] + bb.x; v.y = acc[n][1] + bb.y;
    v.z = acc[n][2] + bb.z; v.w = acc[n][3] + bb.w;
    *reinterpret_cast<float4*>(&Q0V[(size_t)row_o * 64 + col_o]) = v;
  }
}

// ---------------------------------------------------------------------------
// Kernel 3: per-chunk sums of Z.
// ---------------------------------------------------------------------------
__global__ __launch_bounds__(576) void k_chunksum(const float* __restrict__ Q0V,
                                                  const float* __restrict__ decay,
                                                  float* __restrict__ S) {
  const int ch = blockIdx.x;
  const int b  = blockIdx.y;
  __shared__ float vs[TCHUNK * KF];
  __shared__ float dec[TCHUNK];
  const int tid = threadIdx.x;
  const int t0 = ch * TCHUNK;

  for (int idx = tid; idx < TCHUNK * KF; idx += 576) {
    const int t = idx >> 5, j = idx & 31;
    vs[idx] = Q0V[(size_t)(b * T_SEQ + t0 + t) * 64 + KF + j];
  }
  if (tid < TCHUNK) dec[tid] = decay[t0 + tid];
  __syncthreads();

  if (tid >= CPDIM) return;
  const int c = tid;
  int i = 0, rem = c;
  while (rem >= KF - i) { rem -= KF - i; ++i; }
  const int j = i + rem;
  const float sc = (i == j) ? 1.0f : 1.41421356237309515f;
  float h = 0.f;
#pragma unroll 4
  for (int t = 0; t < TCHUNK; ++t)
    h = fmaf(vs[t * KF + i] * vs[t * KF + j], dec[t], h);
  S[(size_t)(b * NCHUNK + ch) * CPDIM + c] = h * sc;
}

// ---------------------------------------------------------------------------
// Kernel 4: exclusive scan of chunk sums (in place).
// ---------------------------------------------------------------------------
__global__ __launch_bounds__(576) void k_scanchunks(float* __restrict__ S) {
  const int b = blockIdx.x;
  const int c = threadIdx.x;
  if (c >= CPDIM) return;
  float run = 0.f;
  for (int ch = 0; ch < NCHUNK; ++ch) {
    const size_t idx = (size_t)(b * NCHUNK + ch) * CPDIM + c;
    const float v = S[idx];
    S[idx] = run;
    run += v;
  }
}

// ---------------------------------------------------------------------------
// Kernel 5: replay scan, expand Q, write Ypk = packsplit(Q*H) (u32).
// ---------------------------------------------------------------------------
__global__ __launch_bounds__(576) void k_scan_y(const float* __restrict__ Q0V,
                                                const float* __restrict__ S,
                                                const float* __restrict__ qp_w,
                                                const float* __restrict__ qp_b,
                                                const float* __restrict__ decay,
                                                unsigned* __restrict__ Ypk) {
  const int ch = blockIdx.x;
  const int b  = blockIdx.y;
  __shared__ float vs[TCHUNK * KF];
  __shared__ float qs[TCHUNK * KF];
  __shared__ float dec[TCHUNK];
  const int tid = threadIdx.x;
  const int t0 = ch * TCHUNK;

  for (int idx = tid; idx < TCHUNK * KF; idx += 576) {
    const int t = idx >> 5, j = idx & 31;
    const size_t row = (size_t)(b * T_SEQ + t0 + t) * 64;
    qs[idx] = Q0V[row + j];
    vs[idx] = Q0V[row + KF + j];
  }
  if (tid < TCHUNK) dec[tid] = decay[t0 + tid];
  __syncthreads();

  if (tid >= CPDIM) return;
  const int c = tid;
  int i = 0, rem = c;
  while (rem >= KF - i) { rem -= KF - i; ++i; }
  const int j = i + rem;
  const float sc = (i == j) ? 1.0f : 1.41421356237309515f;

  float w[KF];
#pragma unroll
  for (int q = 0; q < KF; ++q) w[q] = qp_w[c * KF + q];
  const float qb = qp_b[c];

  float h = S[(size_t)(b * NCHUNK + ch) * CPDIM + c];
  for (int t = 0; t < TCHUNK; ++t) {
    const float z = vs[t * KF + i] * vs[t * KF + j] * sc * dec[t];
    h += z;
    float qv = qb;
#pragma unroll
    for (int q = 0; q < KF; ++q) qv = fmaf(w[q], qs[t * KF + q], qv);
    Ypk[(size_t)(b * T_SEQ + t0 + t) * CPDIM + c] = packsplit(qv * h);
  }
}

// ---------------------------------------------------------------------------
// Kernel 5b: pack o_w to hi/lo u32.
// ---------------------------------------------------------------------------
__global__ __launch_bounds__(256) void k_owpk(const float* __restrict__ ow,
                                              unsigned* __restrict__ owpk) {
  const int idx = blockIdx.x * 256 + threadIdx.x;
  if (idx < DM * CPDIM) owpk[idx] = packsplit(ow[idx]);
}

// ---------------------------------------------------------------------------
// Kernel 6: out = Y @ o_w^T + o_b via 3-term bf16 split MFMA from packed u32.
// 128x128 tile, BK=32, 256 threads, register prefetch, XCD-swizzled grid.
// ---------------------------------------------------------------------------
__global__ __launch_bounds__(256) void k_out_mfma(const unsigned* __restrict__ Ypk,
                                                  const unsigned* __restrict__ owpk,
                                                  const float* __restrict__ ob,
                                                  float* __restrict__ out) {
  __shared__ unsigned short Ahi[128 * 40];
  __shared__ unsigned short Alo[128 * 40];
  __shared__ unsigned short Bhi[128 * 40];
  __shared__ unsigned short Blo[128 * 40];

  // bijective XCD swizzle: 2048 wg = 8 XCD * 256; each XCD gets 32 m-panels x 8 n
  const int wg = blockIdx.x;
  const int nb = (wg & 7) * 256 + (wg >> 3);
  const int m0 = (nb >> 3) * 128;
  const int n0 = (nb & 7) * 128;

  const int tid = threadIdx.x;
  const int w = tid >> 6, l = tid & 63;
  const int wr = w >> 1, wc = w & 1;
  const int g = l >> 4, r = l & 15;
  const int lrow = tid >> 3;    // 0..31
  const int lq = tid & 7;

  f32x4 acc[4][4] = {};
  uint4 a4[4], b4[4];

  {
    const int colv = lq * 4;
#pragma unroll
    for (int r4 = 0; r4 < 4; ++r4) {
      a4[r4] = *reinterpret_cast<const uint4*>(&Ypk [(size_t)(m0 + lrow + r4 * 32) * CPDIM + colv]);
      b4[r4] = *reinterpret_cast<const uint4*>(&owpk[(size_t)(n0 + lrow + r4 * 32) * CPDIM + colv]);
    }
  }

  for (int k0 = 0; k0 < CPDIM; k0 += 32) {
    __syncthreads();
#pragma unroll
    for (int r4 = 0; r4 < 4; ++r4) {
      const int off = (lrow + r4 * 32) * 40 + lq * 4;
      unpack_store(a4[r4], &Ahi[off], &Alo[off]);
      unpack_store(b4[r4], &Bhi[off], &Blo[off]);
    }
    if (k0 + 32 < CPDIM) {
      const int colv = k0 + 32 + lq * 4;
      const bool ok = (colv + 3) < CPDIM;
#pragma unroll
      for (int r4 = 0; r4 < 4; ++r4) {
        if (ok) {
          a4[r4] = *reinterpret_cast<const uint4*>(&Ypk [(size_t)(m0 + lrow + r4 * 32) * CPDIM + colv]);
          b4[r4] = *reinterpret_cast<const uint4*>(&owpk[(size_t)(n0 + lrow + r4 * 32) * CPDIM + colv]);
        } else {
          a4[r4] = make_uint4(0, 0, 0, 0);
          b4[r4] = make_uint4(0, 0, 0, 0);
        }
      }
    }
    __syncthreads();

    bf16x8 fah[4], fal[4], fbh[4], fbl[4];
#pragma unroll
    for (int m = 0; m < 4; ++m) {
      const int off = (wr * 64 + m * 16 + r) * 40 + g * 8;
      fah[m] = *reinterpret_cast<const bf16x8*>(&Ahi[off]);
      fal[m] = *reinterpret_cast<const bf16x8*>(&Alo[off]);
    }
#pragma unroll
    for (int n = 0; n < 4; ++n) {
      const int off = (wc * 64 + n * 16 + r) * 40 + g * 8;
      fbh[n] = *reinterpret_cast<const bf16x8*>(&Bhi[off]);
      fbl[n] = *reinterpret_cast<const bf16x8*>(&Blo[off]);
    }

#pragma unroll
    for (int m = 0; m < 4; ++m)
#pragma unroll
      for (int n = 0; n < 4; ++n) {
        acc[m][n] = __builtin_amdgcn_mfma_f32_16x16x32_bf16(fbh[n], fah[m], acc[m][n], 0, 0, 0);
        acc[m][n] = __builtin_amdgcn_mfma_f32_16x16x32_bf16(fbh[n], fal[m], acc[m][n], 0, 0, 0);
        acc[m][n] = __builtin_amdgcn_mfma_f32_16x16x32_bf16(fbl[n], fah[m], acc[m][n], 0, 0, 0);
      }
  }

  // D row-idx(g*4+j) <-> W side (out col), col-idx(r) <-> Y side (out row)
#pragma unroll
  for (int m = 0; m < 4; ++m) {
    const int row_o = m0 + wr * 64 + m * 16 + r;
#pragma unroll
    for (int n = 0; n < 4; ++n) {
      const int col_o = n0 + wc * 64 + n * 16 + g * 4;
      const float4 bb = *reinterpret_cast<const float4*>(&ob[col_o]);
      float4 v;
      v.x = acc[m][n][0] + bb.x; v.y = acc[m][n][1] + bb.y;
      v.z = acc[m][n][2] + bb.z; v.w = acc[m][n][3] + bb.w;
      *reinterpret_cast<float4*>(&out[(size_t)row_o * DM + col_o]) = v;
    }
  }
}

// ---------------------------------------------------------------------------
extern "C" void kernel_launch(void* const* d_in, const int* in_sizes, int n_in,
                              void* d_out, int out_size, void* d_ws, size_t ws_size,
                              hipStream_t stream) {
  const float* x      = (const float*)d_in[0];
  const float* pre_w  = (const float*)d_in[1];
  const float* pre_b  = (const float*)d_in[2];
  const float* q_filt = (const float*)d_in[3];
  const float* k_filt = (const float*)d_in[4];
  const float* qp_w   = (const float*)d_in[5];
  const float* qp_b   = (const float*)d_in[6];
  const float* o_w    = (const float*)d_in[7];
  const float* o_b    = (const float*)d_in[8];
  const float* decay  = (const float*)d_in[9];
  float* out = (float*)d_out;

  char* ws = (char*)d_ws;
  unsigned short* Wt_hi = (unsigned short*)(ws);            // 128 KB
  unsigned short* Wt_lo = (unsigned short*)(ws + 131072);   // 128 KB
  float*    bias64 = (float*)(ws + 262144);                 // 256 B
  float*    Q0V    = (float*)(ws + 262400);                 // 8.39 MB
  unsigned* owpk   = (unsigned*)(ws + 262400);              // 2.16 MB, ALIASES Q0V
                                                            // (written after Q0V dead)
  float*    S      = (float*)(ws + 8651008);                // 1.08 MB
  unsigned* Ypk    = (unsigned*)(ws + 9732352);             // 69.2 MB
  // total 78.94 MB (same as round 1)

  k_fold<<<dim3(DM / 4), dim3(256), 0, stream>>>(pre_w, q_filt, k_filt, Wt_hi, Wt_lo);
  k_bias<<<dim3(1), dim3(256), 0, stream>>>(pre_b, q_filt, k_filt, bias64);
  k_q0v<<<dim3(MROWS / 128), dim3(512), 0, stream>>>(x, Wt_hi, Wt_lo, bias64, Q0V);
  k_chunksum<<<dim3(NCHUNK, BATCH), dim3(576), 0, stream>>>(Q0V, decay, S);
  k_scanchunks<<<dim3(BATCH), dim3(576), 0, stream>>>(S);
  k_scan_y<<<dim3(NCHUNK, BATCH), dim3(576), 0, stream>>>(Q0V, S, qp_w, qp_b, decay, Ypk);
  k_owpk<<<dim3((DM * CPDIM + 255) / 256), dim3(256), 0, stream>>>(o_w, owpk);  // after Q0V last use
  k_out_mfma<<<dim3((MROWS / 128) * (DM / 128)), dim3(256), 0, stream>>>(Ypk, owpk, o_b, out);
}

// Round 4
// 348.791 us; speedup vs baseline: 2.8290x; 1.0297x over previous
//
#include <hip/hip_runtime.h>
#include <hip/hip_bf16.h>
#include <math.h>

#define T_SEQ   2048
#define DM      1024
#define KF      32
#define BATCH   16
#define CPDIM   528
#define MROWS   (BATCH * T_SEQ)   // 32768
#define NCHUNK  32
#define TCHUNK  64

typedef __bf16 bf16x8 __attribute__((ext_vector_type(8)));
typedef float f32x4 __attribute__((ext_vector_type(4)));
typedef unsigned uint2v __attribute__((ext_vector_type(2)));

// split v into bf16 hi (RNE) + bf16 lo (trunc of residual), packed (hi<<16)|lo
__device__ __forceinline__ unsigned packsplit(float v) {
  unsigned u = __float_as_uint(v);
  unsigned h = (u + 0x7fffu + ((u >> 16) & 1u)) & 0xffff0000u;
  float rr = v - __uint_as_float(h);
  return h | (__float_as_uint(rr) >> 16);
}

// 4 packed u32 -> 4 hi halves + 4 lo halves (k-ascending), stored as 8B each
__device__ __forceinline__ void unpack_store(uint4 q, unsigned short* hi, unsigned short* lo) {
  unsigned hi01 = (q.x >> 16) | (q.y & 0xffff0000u);
  unsigned hi23 = (q.z >> 16) | (q.w & 0xffff0000u);
  unsigned lo01 = (q.x & 0xffffu) | (q.y << 16);
  unsigned lo23 = (q.z & 0xffffu) | (q.w << 16);
  uint2v h2 = {hi01, hi23};
  uint2v l2 = {lo01, lo23};
  *reinterpret_cast<uint2v*>(hi) = h2;
  *reinterpret_cast<uint2v*>(lo) = l2;
}

// ---------------------------------------------------------------------------
// Kernel 1: fold filters through pre_w -> Wt hi/lo bf16, transposed [64][1024].
// Block 0 additionally folds pre_b -> bias64 (reuses the staged filter tile).
// ---------------------------------------------------------------------------
__global__ __launch_bounds__(256) void k_fold(const float* __restrict__ pre_w,
                                              const float* __restrict__ pre_b,
                                              const float* __restrict__ qf,
                                              const float* __restrict__ kfil,
                                              unsigned short* __restrict__ Wt_hi,
                                              unsigned short* __restrict__ Wt_lo,
                                              float* __restrict__ bias64) {
  const int i0 = blockIdx.x * 4;
  const int tid = threadIdx.x;
  const int k = tid & 63;
  const int iq = tid >> 6;
  const int i = i0 + iq;
  __shared__ float fs[64][64];
  __shared__ float ps[64][4];
  __shared__ float pb[64];
  float acc = 0.f, accb = 0.f;
  const bool dobias = (blockIdx.x == 0) && (iq == 0);
  for (int s0 = 0; s0 < T_SEQ; s0 += 64) {
    __syncthreads();
    for (int idx = tid; idx < 64 * 64; idx += 256) {
      const int s = idx >> 6, kk = idx & 63;
      fs[s][kk] = (kk < KF) ? qf[(s0 + s) * KF + kk] : kfil[(s0 + s) * KF + kk - KF];
    }
    {
      const int s = tid >> 2, ii = tid & 3;
      ps[s][ii] = pre_w[(size_t)(s0 + s) * DM + i0 + ii];
    }
    if (tid < 64) pb[tid] = pre_b[s0 + tid];
    __syncthreads();
#pragma unroll 8
    for (int s = 0; s < 64; ++s)
      acc = fmaf(ps[s][iq], fs[s][k], acc);
    if (dobias) {
#pragma unroll 8
      for (int s = 0; s < 64; ++s)
        accb = fmaf(pb[s], fs[s][k], accb);
    }
  }
  const unsigned pk = packsplit(acc);
  Wt_hi[(size_t)k * DM + i] = (unsigned short)(pk >> 16);
  Wt_lo[(size_t)k * DM + i] = (unsigned short)(pk & 0xffffu);
  if (dobias) bias64[k] = accb;
}

// ---------------------------------------------------------------------------
// Kernel 2: Q0V = x @ Wt^T + bias64 via 3-term bf16 split MFMA.
// ---------------------------------------------------------------------------
__global__ __launch_bounds__(512) void k_q0v(const float* __restrict__ x,
                                             const unsigned short* __restrict__ Wt_hi,
                                             const unsigned short* __restrict__ Wt_lo,
                                             const float* __restrict__ bias64,
                                             float* __restrict__ Q0V) {
  __shared__ unsigned short Ahi[128 * 40];
  __shared__ unsigned short Alo[128 * 40];
  const int tid = threadIdx.x;
  const int m0 = blockIdx.x * 128;
  const int w = tid >> 6;
  const int l = tid & 63;
  const int g = l >> 4, r = l & 15;
  const int lrow = tid >> 3;
  const int lq = tid & 7;

  f32x4 acc[4] = {};

  float4 fa[2];
#pragma unroll
  for (int r4 = 0; r4 < 2; ++r4)
    fa[r4] = *reinterpret_cast<const float4*>(&x[(size_t)(m0 + lrow + r4 * 64) * DM + lq * 4]);

  for (int k0 = 0; k0 < DM; k0 += 32) {
    __syncthreads();
#pragma unroll
    for (int r4 = 0; r4 < 2; ++r4) {
      const unsigned p0 = packsplit(fa[r4].x);
      const unsigned p1 = packsplit(fa[r4].y);
      const unsigned p2 = packsplit(fa[r4].z);
      const unsigned p3 = packsplit(fa[r4].w);
      uint2v h2 = {(p0 >> 16) | (p1 & 0xffff0000u), (p2 >> 16) | (p3 & 0xffff0000u)};
      uint2v l2 = {(p0 & 0xffffu) | (p1 << 16),     (p2 & 0xffffu) | (p3 << 16)};
      const int off = (lrow + r4 * 64) * 40 + lq * 4;
      *reinterpret_cast<uint2v*>(&Ahi[off]) = h2;
      *reinterpret_cast<uint2v*>(&Alo[off]) = l2;
    }
    if (k0 + 32 < DM) {
#pragma unroll
      for (int r4 = 0; r4 < 2; ++r4)
        fa[r4] = *reinterpret_cast<const float4*>(&x[(size_t)(m0 + lrow + r4 * 64) * DM + k0 + 32 + lq * 4]);
    }
    bf16x8 bh[4], bl[4];
#pragma unroll
    for (int n = 0; n < 4; ++n) {
      const size_t boff = (size_t)(n * 16 + r) * DM + k0 + g * 8;
      bh[n] = *reinterpret_cast<const bf16x8*>(&Wt_hi[boff]);
      bl[n] = *reinterpret_cast<const bf16x8*>(&Wt_lo[boff]);
    }
    __syncthreads();
    const int aoff = (w * 16 + r) * 40 + g * 8;
    const bf16x8 ah = *reinterpret_cast<const bf16x8*>(&Ahi[aoff]);
    const bf16x8 al = *reinterpret_cast<const bf16x8*>(&Alo[aoff]);
#pragma unroll
    for (int n = 0; n < 4; ++n) {
      acc[n] = __builtin_amdgcn_mfma_f32_16x16x32_bf16(bh[n], ah, acc[n], 0, 0, 0);
      acc[n] = __builtin_amdgcn_mfma_f32_16x16x32_bf16(bh[n], al, acc[n], 0, 0, 0);
      acc[n] = __builtin_amdgcn_mfma_f32_16x16x32_bf16(bl[n], ah, acc[n], 0, 0, 0);
    }
  }
  const int row_o = m0 + w * 16 + r;
#pragma unroll
  for (int n = 0; n < 4; ++n) {
    const int col_o = n * 16 + g * 4;
    const float4 bb = *reinterpret_cast<const float4*>(&bias64[col_o]);
    float4 v;
    v.x = acc[n][0] + bb.x; v.y = acc[n][1] + bb.y;
    v.z = acc[n][2] + bb.z; v.w = acc[n][3] + bb.w;
    *reinterpret_cast<float4*>(&Q0V[(size_t)row_o * 64 + col_o]) = v;
  }
}

// ---------------------------------------------------------------------------
// Kernel 3: per-chunk sums of Z.
// ---------------------------------------------------------------------------
__global__ __launch_bounds__(576) void k_chunksum(const float* __restrict__ Q0V,
                                                  const float* __restrict__ decay,
                                                  float* __restrict__ S) {
  const int ch = blockIdx.x;
  const int b  = blockIdx.y;
  __shared__ float vs[TCHUNK * KF];
  __shared__ float dec[TCHUNK];
  const int tid = threadIdx.x;
  const int t0 = ch * TCHUNK;

  for (int idx = tid; idx < TCHUNK * KF; idx += 576) {
    const int t = idx >> 5, j = idx & 31;
    vs[idx] = Q0V[(size_t)(b * T_SEQ + t0 + t) * 64 + KF + j];
  }
  if (tid < TCHUNK) dec[tid] = decay[t0 + tid];
  __syncthreads();

  if (tid >= CPDIM) return;
  const int c = tid;
  int i = 0, rem = c;
  while (rem >= KF - i) { rem -= KF - i; ++i; }
  const int j = i + rem;
  const float sc = (i == j) ? 1.0f : 1.41421356237309515f;
  float h = 0.f;
#pragma unroll 4
  for (int t = 0; t < TCHUNK; ++t)
    h = fmaf(vs[t * KF + i] * vs[t * KF + j], dec[t], h);
  S[(size_t)(b * NCHUNK + ch) * CPDIM + c] = h * sc;
}

// ---------------------------------------------------------------------------
// Kernel 4: exclusive scan of chunk sums (in place), register-batched loads.
// ---------------------------------------------------------------------------
__global__ __launch_bounds__(576) void k_scanchunks(float* __restrict__ S) {
  const int b = blockIdx.x;
  const int c = threadIdx.x;
  if (c >= CPDIM) return;
  float v[NCHUNK];
#pragma unroll
  for (int ch = 0; ch < NCHUNK; ++ch)
    v[ch] = S[(size_t)(b * NCHUNK + ch) * CPDIM + c];
  float run = 0.f;
#pragma unroll
  for (int ch = 0; ch < NCHUNK; ++ch) {
    S[(size_t)(b * NCHUNK + ch) * CPDIM + c] = run;
    run += v[ch];
  }
}

// ---------------------------------------------------------------------------
// Kernel 5: replay scan, expand Q, write Ypk = packsplit(Q*H) (u32).
// ---------------------------------------------------------------------------
__global__ __launch_bounds__(576) void k_scan_y(const float* __restrict__ Q0V,
                                                const float* __restrict__ S,
                                                const float* __restrict__ qp_w,
                                                const float* __restrict__ qp_b,
                                                const float* __restrict__ decay,
                                                unsigned* __restrict__ Ypk) {
  const int ch = blockIdx.x;
  const int b  = blockIdx.y;
  __shared__ float vs[TCHUNK * KF];
  __shared__ float qs[TCHUNK * KF];
  __shared__ float dec[TCHUNK];
  const int tid = threadIdx.x;
  const int t0 = ch * TCHUNK;

  for (int idx = tid; idx < TCHUNK * KF; idx += 576) {
    const int t = idx >> 5, j = idx & 31;
    const size_t row = (size_t)(b * T_SEQ + t0 + t) * 64;
    qs[idx] = Q0V[row + j];
    vs[idx] = Q0V[row + KF + j];
  }
  if (tid < TCHUNK) dec[tid] = decay[t0 + tid];
  __syncthreads();

  if (tid >= CPDIM) return;
  const int c = tid;
  int i = 0, rem = c;
  while (rem >= KF - i) { rem -= KF - i; ++i; }
  const int j = i + rem;
  const float sc = (i == j) ? 1.0f : 1.41421356237309515f;

  float w[KF];
#pragma unroll
  for (int q = 0; q < KF; ++q) w[q] = qp_w[c * KF + q];
  const float qb = qp_b[c];

  float h = S[(size_t)(b * NCHUNK + ch) * CPDIM + c];
  for (int t = 0; t < TCHUNK; ++t) {
    const float z = vs[t * KF + i] * vs[t * KF + j] * sc * dec[t];
    h += z;
    float qv = qb;
#pragma unroll
    for (int q = 0; q < KF; ++q) qv = fmaf(w[q], qs[t * KF + q], qv);
    Ypk[(size_t)(b * T_SEQ + t0 + t) * CPDIM + c] = packsplit(qv * h);
  }
}

// ---------------------------------------------------------------------------
// Kernel 5b: pack o_w to hi/lo u32.
// ---------------------------------------------------------------------------
__global__ __launch_bounds__(256) void k_owpk(const float* __restrict__ ow,
                                              unsigned* __restrict__ owpk) {
  const int idx = blockIdx.x * 256 + threadIdx.x;
  if (idx < DM * CPDIM) owpk[idx] = packsplit(ow[idx]);
}

// ---------------------------------------------------------------------------
// Kernel 6: out = Y @ o_w^T + o_b via 3-term bf16 split MFMA from packed u32.
// 128x128 tile, BK=32, double-buffered LDS (80 KB), ONE barrier per K-step,
// register prefetch 2 steps ahead, XCD-swizzled grid.
// ---------------------------------------------------------------------------
__global__ __launch_bounds__(256) void k_out_mfma(const unsigned* __restrict__ Ypk,
                                                  const unsigned* __restrict__ owpk,
                                                  const float* __restrict__ ob,
                                                  float* __restrict__ out) {
  __shared__ unsigned short Ahi[2][128 * 40];
  __shared__ unsigned short Alo[2][128 * 40];
  __shared__ unsigned short Bhi[2][128 * 40];
  __shared__ unsigned short Blo[2][128 * 40];

  const int wg = blockIdx.x;
  const int nb = (wg & 7) * 256 + (wg >> 3);
  const int m0 = (nb >> 3) * 128;
  const int n0 = (nb & 7) * 128;

  const int tid = threadIdx.x;
  const int w = tid >> 6, l = tid & 63;
  const int wr = w >> 1, wc = w & 1;
  const int g = l >> 4, r = l & 15;
  const int lrow = tid >> 3;    // 0..31
  const int lq = tid & 7;

  f32x4 acc[4][4] = {};
  uint4 a4[4], b4[4];

  // load step 0
#pragma unroll
  for (int r4 = 0; r4 < 4; ++r4) {
    a4[r4] = *reinterpret_cast<const uint4*>(&Ypk [(size_t)(m0 + lrow + r4 * 32) * CPDIM + lq * 4]);
    b4[r4] = *reinterpret_cast<const uint4*>(&owpk[(size_t)(n0 + lrow + r4 * 32) * CPDIM + lq * 4]);
  }
  // write buf0
#pragma unroll
  for (int r4 = 0; r4 < 4; ++r4) {
    const int off = (lrow + r4 * 32) * 40 + lq * 4;
    unpack_store(a4[r4], &Ahi[0][off], &Alo[0][off]);
    unpack_store(b4[r4], &Bhi[0][off], &Blo[0][off]);
  }
  // load step 1
  {
    const int colv = 32 + lq * 4;
#pragma unroll
    for (int r4 = 0; r4 < 4; ++r4) {
      a4[r4] = *reinterpret_cast<const uint4*>(&Ypk [(size_t)(m0 + lrow + r4 * 32) * CPDIM + colv]);
      b4[r4] = *reinterpret_cast<const uint4*>(&owpk[(size_t)(n0 + lrow + r4 * 32) * CPDIM + colv]);
    }
  }
  __syncthreads();

  for (int k0 = 0, it = 0; k0 < CPDIM; k0 += 32, ++it) {
    const int cur = it & 1, nxt = cur ^ 1;

    // stage next step's data (regs -> LDS[nxt]); overlaps other waves' MFMA
    if (k0 + 32 < CPDIM) {
#pragma unroll
      for (int r4 = 0; r4 < 4; ++r4) {
        const int off = (lrow + r4 * 32) * 40 + lq * 4;
        unpack_store(a4[r4], &Ahi[nxt][off], &Alo[nxt][off]);
        unpack_store(b4[r4], &Bhi[nxt][off], &Blo[nxt][off]);
      }
    }
    // prefetch step+2 into regs
    if (k0 + 64 < CPDIM) {
      const int colv = k0 + 64 + lq * 4;
      const bool ok = (colv + 3) < CPDIM;
#pragma unroll
      for (int r4 = 0; r4 < 4; ++r4) {
        if (ok) {
          a4[r4] = *reinterpret_cast<const uint4*>(&Ypk [(size_t)(m0 + lrow + r4 * 32) * CPDIM + colv]);
          b4[r4] = *reinterpret_cast<const uint4*>(&owpk[(size_t)(n0 + lrow + r4 * 32) * CPDIM + colv]);
        } else {
          a4[r4] = make_uint4(0, 0, 0, 0);
          b4[r4] = make_uint4(0, 0, 0, 0);
        }
      }
    }

    // fragments from LDS[cur]
    bf16x8 fah[4], fal[4], fbh[4], fbl[4];
#pragma unroll
    for (int m = 0; m < 4; ++m) {
      const int off = (wr * 64 + m * 16 + r) * 40 + g * 8;
      fah[m] = *reinterpret_cast<const bf16x8*>(&Ahi[cur][off]);
      fal[m] = *reinterpret_cast<const bf16x8*>(&Alo[cur][off]);
    }
#pragma unroll
    for (int n = 0; n < 4; ++n) {
      const int off = (wc * 64 + n * 16 + r) * 40 + g * 8;
      fbh[n] = *reinterpret_cast<const bf16x8*>(&Bhi[cur][off]);
      fbl[n] = *reinterpret_cast<const bf16x8*>(&Blo[cur][off]);
    }

#pragma unroll
    for (int m = 0; m < 4; ++m)
#pragma unroll
      for (int n = 0; n < 4; ++n) {
        acc[m][n] = __builtin_amdgcn_mfma_f32_16x16x32_bf16(fbh[n], fah[m], acc[m][n], 0, 0, 0);
        acc[m][n] = __builtin_amdgcn_mfma_f32_16x16x32_bf16(fbh[n], fal[m], acc[m][n], 0, 0, 0);
        acc[m][n] = __builtin_amdgcn_mfma_f32_16x16x32_bf16(fbl[n], fah[m], acc[m][n], 0, 0, 0);
      }

    __syncthreads();
  }

  // D row-idx(g*4+j) <-> W side (out col), col-idx(r) <-> Y side (out row)
#pragma unroll
  for (int m = 0; m < 4; ++m) {
    const int row_o = m0 + wr * 64 + m * 16 + r;
#pragma unroll
    for (int n = 0; n < 4; ++n) {
      const int col_o = n0 + wc * 64 + n * 16 + g * 4;
      const float4 bb = *reinterpret_cast<const float4*>(&ob[col_o]);
      float4 v;
      v.x = acc[m][n][0] + bb.x; v.y = acc[m][n][1] + bb.y;
      v.z = acc[m][n][2] + bb.z; v.w = acc[m][n][3] + bb.w;
      *reinterpret_cast<float4*>(&out[(size_t)row_o * DM + col_o]) = v;
    }
  }
}

// ---------------------------------------------------------------------------
extern "C" void kernel_launch(void* const* d_in, const int* in_sizes, int n_in,
                              void* d_out, int out_size, void* d_ws, size_t ws_size,
                              hipStream_t stream) {
  const float* x      = (const float*)d_in[0];
  const float* pre_w  = (const float*)d_in[1];
  const float* pre_b  = (const float*)d_in[2];
  const float* q_filt = (const float*)d_in[3];
  const float* k_filt = (const float*)d_in[4];
  const float* qp_w   = (const float*)d_in[5];
  const float* qp_b   = (const float*)d_in[6];
  const float* o_w    = (const float*)d_in[7];
  const float* o_b    = (const float*)d_in[8];
  const float* decay  = (const float*)d_in[9];
  float* out = (float*)d_out;

  char* ws = (char*)d_ws;
  unsigned short* Wt_hi = (unsigned short*)(ws);            // 128 KB
  unsigned short* Wt_lo = (unsigned short*)(ws + 131072);   // 128 KB
  float*    bias64 = (float*)(ws + 262144);                 // 256 B
  float*    Q0V    = (float*)(ws + 262400);                 // 8.39 MB
  unsigned* owpk   = (unsigned*)(ws + 262400);              // 2.16 MB, ALIASES Q0V
                                                            // (written after Q0V dead)
  float*    S      = (float*)(ws + 8651008);                // 1.08 MB
  unsigned* Ypk    = (unsigned*)(ws + 9732352);             // 69.2 MB
  // total 78.94 MB

  k_fold<<<dim3(DM / 4), dim3(256), 0, stream>>>(pre_w, pre_b, q_filt, k_filt, Wt_hi, Wt_lo, bias64);
  k_q0v<<<dim3(MROWS / 128), dim3(512), 0, stream>>>(x, Wt_hi, Wt_lo, bias64, Q0V);
  k_chunksum<<<dim3(NCHUNK, BATCH), dim3(576), 0, stream>>>(Q0V, decay, S);
  k_scanchunks<<<dim3(BATCH), dim3(576), 0, stream>>>(S);
  k_scan_y<<<dim3(NCHUNK, BATCH), dim3(576), 0, stream>>>(Q0V, S, qp_w, qp_b, decay, Ypk);
  k_owpk<<<dim3((DM * CPDIM + 255) / 256), dim3(256), 0, stream>>>(o_w, owpk);  // after Q0V last use
  k_out_mfma<<<dim3((MROWS / 128) * (DM / 128)), dim3(256), 0, stream>>>(Ypk, owpk, o_b, out);
}

// Round 5
// 280.758 us; speedup vs baseline: 3.5146x; 1.2423x over previous
//
#include <hip/hip_runtime.h>
#include <hip/hip_bf16.h>
#include <math.h>

#define T_SEQ   2048
#define DM      1024
#define KF      32
#define BATCH   16
#define CPDIM   528
#define KPAD    576               // CPDIM padded to 9*64 for the final GEMM
#define MROWS   (BATCH * T_SEQ)   // 32768
#define NCHUNK  32
#define TCHUNK  64

typedef __bf16 bf16x8 __attribute__((ext_vector_type(8)));
typedef float f32x4 __attribute__((ext_vector_type(4)));
typedef unsigned uint2v __attribute__((ext_vector_type(2)));

// split v into bf16 hi (RNE) + bf16 lo (trunc of residual), packed (hi<<16)|lo
__device__ __forceinline__ unsigned packsplit(float v) {
  unsigned u = __float_as_uint(v);
  unsigned h = (u + 0x7fffu + ((u >> 16) & 1u)) & 0xffff0000u;
  float rr = v - __uint_as_float(h);
  return h | (__float_as_uint(rr) >> 16);
}

// RNE f32 -> bf16 (as u16)
__device__ __forceinline__ unsigned short f2bf(float f) {
  unsigned u = __float_as_uint(f);
  return (unsigned short)((u + 0x7fffu + ((u >> 16) & 1u)) >> 16);
}

// async global->LDS, 16 bytes per lane (dest = wave-uniform base + lane*16)
__device__ __forceinline__ void gload16(const void* g, void* l) {
  __builtin_amdgcn_global_load_lds(
      (const __attribute__((address_space(1))) unsigned*)g,
      (__attribute__((address_space(3))) unsigned*)l, 16, 0, 0);
}

// ---------------------------------------------------------------------------
// Kernel 1: fold filters through pre_w -> Wt hi/lo bf16, transposed [64][1024].
// Block 0 additionally folds pre_b -> bias64.
// ---------------------------------------------------------------------------
__global__ __launch_bounds__(256) void k_fold(const float* __restrict__ pre_w,
                                              const float* __restrict__ pre_b,
                                              const float* __restrict__ qf,
                                              const float* __restrict__ kfil,
                                              unsigned short* __restrict__ Wt_hi,
                                              unsigned short* __restrict__ Wt_lo,
                                              float* __restrict__ bias64) {
  const int i0 = blockIdx.x * 4;
  const int tid = threadIdx.x;
  const int k = tid & 63;
  const int iq = tid >> 6;
  const int i = i0 + iq;
  __shared__ float fs[64][64];
  __shared__ float ps[64][4];
  __shared__ float pb[64];
  float acc = 0.f, accb = 0.f;
  const bool dobias = (blockIdx.x == 0) && (iq == 0);
  for (int s0 = 0; s0 < T_SEQ; s0 += 64) {
    __syncthreads();
    for (int idx = tid; idx < 64 * 64; idx += 256) {
      const int s = idx >> 6, kk = idx & 63;
      fs[s][kk] = (kk < KF) ? qf[(s0 + s) * KF + kk] : kfil[(s0 + s) * KF + kk - KF];
    }
    {
      const int s = tid >> 2, ii = tid & 3;
      ps[s][ii] = pre_w[(size_t)(s0 + s) * DM + i0 + ii];
    }
    if (tid < 64) pb[tid] = pre_b[s0 + tid];
    __syncthreads();
#pragma unroll 8
    for (int s = 0; s < 64; ++s)
      acc = fmaf(ps[s][iq], fs[s][k], acc);
    if (dobias) {
#pragma unroll 8
      for (int s = 0; s < 64; ++s)
        accb = fmaf(pb[s], fs[s][k], accb);
    }
  }
  const unsigned pk = packsplit(acc);
  Wt_hi[(size_t)k * DM + i] = (unsigned short)(pk >> 16);
  Wt_lo[(size_t)k * DM + i] = (unsigned short)(pk & 0xffffu);
  if (dobias) bias64[k] = accb;
}

// ---------------------------------------------------------------------------
// Kernel 2: Q0V = x @ Wt^T + bias64 via 3-term bf16 split MFMA (exact split —
// V feeds squared terms + cumsum, so k_q0v must stay high precision).
// ---------------------------------------------------------------------------
__global__ __launch_bounds__(512) void k_q0v(const float* __restrict__ x,
                                             const unsigned short* __restrict__ Wt_hi,
                                             const unsigned short* __restrict__ Wt_lo,
                                             const float* __restrict__ bias64,
                                             float* __restrict__ Q0V) {
  __shared__ unsigned short Ahi[128 * 40];
  __shared__ unsigned short Alo[128 * 40];
  const int tid = threadIdx.x;
  const int m0 = blockIdx.x * 128;
  const int w = tid >> 6;
  const int l = tid & 63;
  const int g = l >> 4, r = l & 15;
  const int lrow = tid >> 3;
  const int lq = tid & 7;

  f32x4 acc[4] = {};

  float4 fa[2];
#pragma unroll
  for (int r4 = 0; r4 < 2; ++r4)
    fa[r4] = *reinterpret_cast<const float4*>(&x[(size_t)(m0 + lrow + r4 * 64) * DM + lq * 4]);

  for (int k0 = 0; k0 < DM; k0 += 32) {
    __syncthreads();
#pragma unroll
    for (int r4 = 0; r4 < 2; ++r4) {
      const unsigned p0 = packsplit(fa[r4].x);
      const unsigned p1 = packsplit(fa[r4].y);
      const unsigned p2 = packsplit(fa[r4].z);
      const unsigned p3 = packsplit(fa[r4].w);
      uint2v h2 = {(p0 >> 16) | (p1 & 0xffff0000u), (p2 >> 16) | (p3 & 0xffff0000u)};
      uint2v l2 = {(p0 & 0xffffu) | (p1 << 16),     (p2 & 0xffffu) | (p3 << 16)};
      const int off = (lrow + r4 * 64) * 40 + lq * 4;
      *reinterpret_cast<uint2v*>(&Ahi[off]) = h2;
      *reinterpret_cast<uint2v*>(&Alo[off]) = l2;
    }
    if (k0 + 32 < DM) {
#pragma unroll
      for (int r4 = 0; r4 < 2; ++r4)
        fa[r4] = *reinterpret_cast<const float4*>(&x[(size_t)(m0 + lrow + r4 * 64) * DM + k0 + 32 + lq * 4]);
    }
    bf16x8 bh[4], bl[4];
#pragma unroll
    for (int n = 0; n < 4; ++n) {
      const size_t boff = (size_t)(n * 16 + r) * DM + k0 + g * 8;
      bh[n] = *reinterpret_cast<const bf16x8*>(&Wt_hi[boff]);
      bl[n] = *reinterpret_cast<const bf16x8*>(&Wt_lo[boff]);
    }
    __syncthreads();
    const int aoff = (w * 16 + r) * 40 + g * 8;
    const bf16x8 ah = *reinterpret_cast<const bf16x8*>(&Ahi[aoff]);
    const bf16x8 al = *reinterpret_cast<const bf16x8*>(&Alo[aoff]);
#pragma unroll
    for (int n = 0; n < 4; ++n) {
      acc[n] = __builtin_amdgcn_mfma_f32_16x16x32_bf16(bh[n], ah, acc[n], 0, 0, 0);
      acc[n] = __builtin_amdgcn_mfma_f32_16x16x32_bf16(bh[n], al, acc[n], 0, 0, 0);
      acc[n] = __builtin_amdgcn_mfma_f32_16x16x32_bf16(bl[n], ah, acc[n], 0, 0, 0);
    }
  }
  const int row_o = m0 + w * 16 + r;
#pragma unroll
  for (int n = 0; n < 4; ++n) {
    const int col_o = n * 16 + g * 4;
    const float4 bb = *reinterpret_cast<const float4*>(&bias64[col_o]);
    float4 v;
    v.x = acc[n][0] + bb.x; v.y = acc[n][1] + bb.y;
    v.z = acc[n][2] + bb.z; v.w = acc[n][3] + bb.w;
    *reinterpret_cast<float4*>(&Q0V[(size_t)row_o * 64 + col_o]) = v;
  }
}

// ---------------------------------------------------------------------------
// Kernel 3: per-chunk sums of Z.
// ---------------------------------------------------------------------------
__global__ __launch_bounds__(576) void k_chunksum(const float* __restrict__ Q0V,
                                                  const float* __restrict__ decay,
                                                  float* __restrict__ S) {
  const int ch = blockIdx.x;
  const int b  = blockIdx.y;
  __shared__ float vs[TCHUNK * KF];
  __shared__ float dec[TCHUNK];
  const int tid = threadIdx.x;
  const int t0 = ch * TCHUNK;

  for (int idx = tid; idx < TCHUNK * KF; idx += 576) {
    const int t = idx >> 5, j = idx & 31;
    vs[idx] = Q0V[(size_t)(b * T_SEQ + t0 + t) * 64 + KF + j];
  }
  if (tid < TCHUNK) dec[tid] = decay[t0 + tid];
  __syncthreads();

  if (tid >= CPDIM) return;
  const int c = tid;
  int i = 0, rem = c;
  while (rem >= KF - i) { rem -= KF - i; ++i; }
  const int j = i + rem;
  const float sc = (i == j) ? 1.0f : 1.41421356237309515f;
  float h = 0.f;
#pragma unroll 4
  for (int t = 0; t < TCHUNK; ++t)
    h = fmaf(vs[t * KF + i] * vs[t * KF + j], dec[t], h);
  S[(size_t)(b * NCHUNK + ch) * CPDIM + c] = h * sc;
}

// ---------------------------------------------------------------------------
// Kernel 4: exclusive scan of chunk sums (in place), register-batched loads.
// ---------------------------------------------------------------------------
__global__ __launch_bounds__(576) void k_scanchunks(float* __restrict__ S) {
  const int b = blockIdx.x;
  const int c = threadIdx.x;
  if (c >= CPDIM) return;
  float v[NCHUNK];
#pragma unroll
  for (int ch = 0; ch < NCHUNK; ++ch)
    v[ch] = S[(size_t)(b * NCHUNK + ch) * CPDIM + c];
  float run = 0.f;
#pragma unroll
  for (int ch = 0; ch < NCHUNK; ++ch) {
    S[(size_t)(b * NCHUNK + ch) * CPDIM + c] = run;
    run += v[ch];
  }
}

// ---------------------------------------------------------------------------
// Kernel 5: replay scan, expand Q, write Yb = bf16(Q*H), K-padded to 576.
// ---------------------------------------------------------------------------
__global__ __launch_bounds__(576) void k_scan_y(const float* __restrict__ Q0V,
                                                const float* __restrict__ S,
                                                const float* __restrict__ qp_w,
                                                const float* __restrict__ qp_b,
                                                const float* __restrict__ decay,
                                                unsigned short* __restrict__ Yb) {
  const int ch = blockIdx.x;
  const int b  = blockIdx.y;
  __shared__ float vs[TCHUNK * KF];
  __shared__ float qs[TCHUNK * KF];
  __shared__ float dec[TCHUNK];
  const int tid = threadIdx.x;
  const int t0 = ch * TCHUNK;

  for (int idx = tid; idx < TCHUNK * KF; idx += 576) {
    const int t = idx >> 5, j = idx & 31;
    const size_t row = (size_t)(b * T_SEQ + t0 + t) * 64;
    qs[idx] = Q0V[row + j];
    vs[idx] = Q0V[row + KF + j];
  }
  if (tid < TCHUNK) dec[tid] = decay[t0 + tid];
  __syncthreads();

  const int c = tid;
  if (c >= CPDIM) {
    // zero the K-padding columns 528..575
    for (int t = 0; t < TCHUNK; ++t)
      Yb[(size_t)(b * T_SEQ + t0 + t) * KPAD + c] = 0;
    return;
  }
  int i = 0, rem = c;
  while (rem >= KF - i) { rem -= KF - i; ++i; }
  const int j = i + rem;
  const float sc = (i == j) ? 1.0f : 1.41421356237309515f;

  float w[KF];
#pragma unroll
  for (int q = 0; q < KF; ++q) w[q] = qp_w[c * KF + q];
  const float qb = qp_b[c];

  float h = S[(size_t)(b * NCHUNK + ch) * CPDIM + c];
  for (int t = 0; t < TCHUNK; ++t) {
    const float z = vs[t * KF + i] * vs[t * KF + j] * sc * dec[t];
    h += z;
    float qv = qb;
#pragma unroll
    for (int q = 0; q < KF; ++q) qv = fmaf(w[q], qs[t * KF + q], qv);
    Yb[(size_t)(b * T_SEQ + t0 + t) * KPAD + c] = f2bf(qv * h);
  }
}

// ---------------------------------------------------------------------------
// Kernel 5b: o_w -> bf16, K-padded to 576.
// ---------------------------------------------------------------------------
__global__ __launch_bounds__(256) void k_owb(const float* __restrict__ ow,
                                             unsigned short* __restrict__ owb) {
  const int idx = blockIdx.x * 256 + threadIdx.x;
  if (idx >= DM * KPAD) return;
  const int n = idx / KPAD, k = idx - n * KPAD;
  owb[idx] = (k < CPDIM) ? f2bf(ow[(size_t)n * CPDIM + k]) : (unsigned short)0;
}

// ---------------------------------------------------------------------------
// Kernel 6: out = Y @ o_w^T + o_b, single bf16 MFMA (m97 structure).
// M=32768, N=1024, K=576. 128x128 tile, BK=64, 4 waves, global_load_lds x16,
// linear LDS, 2 barriers/K-step, XCD-swizzled grid.
// ---------------------------------------------------------------------------
__global__ __launch_bounds__(256) void k_out_mfma(const unsigned short* __restrict__ Yb,
                                                  const unsigned short* __restrict__ owb,
                                                  const float* __restrict__ ob,
                                                  float* __restrict__ out) {
  __shared__ unsigned short As[128 * 64];   // 16 KB
  __shared__ unsigned short Bs[128 * 64];   // 16 KB

  const int wg = blockIdx.x;
  const int nb = (wg & 7) * 256 + (wg >> 3);
  const int m0 = (nb >> 3) * 128;
  const int n0 = (nb & 7) * 128;

  const int tid = threadIdx.x;
  const int w = tid >> 6, l = tid & 63;
  const int wr = w >> 1, wc = w & 1;
  const int g = l >> 4, r = l & 15;

  f32x4 acc[4][4] = {};

  // stage tile at k0: 128 rows x 64 halves = 16 KB per operand.
  // chunk c = i*256+tid; row=c>>3, colh=(c&7)*8; LDS halves offset = c*8
  // (linear: c*8 == row*64 + colh). Wave-uniform LDS base + lane*16 holds.
  auto stage = [&](int k0) {
#pragma unroll
    for (int i = 0; i < 4; ++i) {
      const int c = i * 256 + tid;
      const int row = c >> 3, colh = (c & 7) * 8;
      gload16(&Yb [(size_t)(m0 + row) * KPAD + k0 + colh], &As[c * 8]);
      gload16(&owb[(size_t)(n0 + row) * KPAD + k0 + colh], &Bs[c * 8]);
    }
  };

  stage(0);
  for (int it = 0; it < KPAD / 64; ++it) {
    __syncthreads();   // implicit vmcnt(0) drain -> tile resident

#pragma unroll
    for (int ksub = 0; ksub < 2; ++ksub) {
      bf16x8 af[4], bf[4];
      const int kh = ksub * 32 + g * 8;
#pragma unroll
      for (int m = 0; m < 4; ++m)
        af[m] = *reinterpret_cast<const bf16x8*>(&As[(wr * 64 + m * 16 + r) * 64 + kh]);
#pragma unroll
      for (int n = 0; n < 4; ++n)
        bf[n] = *reinterpret_cast<const bf16x8*>(&Bs[(wc * 64 + n * 16 + r) * 64 + kh]);
#pragma unroll
      for (int m = 0; m < 4; ++m)
#pragma unroll
        for (int n = 0; n < 4; ++n)
          acc[m][n] = __builtin_amdgcn_mfma_f32_16x16x32_bf16(bf[n], af[m], acc[m][n], 0, 0, 0);
    }

    __syncthreads();   // all waves done reading LDS
    if (it + 1 < KPAD / 64) stage((it + 1) * 64);
  }

  // D row-idx(g*4+j) <-> ow side (out col), col-idx(r) <-> Y side (out row)
#pragma unroll
  for (int m = 0; m < 4; ++m) {
    const int row_o = m0 + wr * 64 + m * 16 + r;
#pragma unroll
    for (int n = 0; n < 4; ++n) {
      const int col_o = n0 + wc * 64 + n * 16 + g * 4;
      const float4 bb = *reinterpret_cast<const float4*>(&ob[col_o]);
      float4 v;
      v.x = acc[m][n][0] + bb.x; v.y = acc[m][n][1] + bb.y;
      v.z = acc[m][n][2] + bb.z; v.w = acc[m][n][3] + bb.w;
      *reinterpret_cast<float4*>(&out[(size_t)row_o * DM + col_o]) = v;
    }
  }
}

// ---------------------------------------------------------------------------
extern "C" void kernel_launch(void* const* d_in, const int* in_sizes, int n_in,
                              void* d_out, int out_size, void* d_ws, size_t ws_size,
                              hipStream_t stream) {
  const float* x      = (const float*)d_in[0];
  const float* pre_w  = (const float*)d_in[1];
  const float* pre_b  = (const float*)d_in[2];
  const float* q_filt = (const float*)d_in[3];
  const float* k_filt = (const float*)d_in[4];
  const float* qp_w   = (const float*)d_in[5];
  const float* qp_b   = (const float*)d_in[6];
  const float* o_w    = (const float*)d_in[7];
  const float* o_b    = (const float*)d_in[8];
  const float* decay  = (const float*)d_in[9];
  float* out = (float*)d_out;

  char* ws = (char*)d_ws;
  unsigned short* Wt_hi = (unsigned short*)(ws);            // 128 KB
  unsigned short* Wt_lo = (unsigned short*)(ws + 131072);   // 128 KB
  float*    bias64 = (float*)(ws + 262144);                 // 256 B
  float*    Q0V    = (float*)(ws + 262400);                 // 8.39 MB
  unsigned short* owb = (unsigned short*)(ws + 262400);     // 1.18 MB, ALIASES Q0V
                                                            // (written after Q0V dead)
  float*    S      = (float*)(ws + 8651008);                // 270 KB
  unsigned short* Yb = (unsigned short*)(ws + 9732352);     // 37.75 MB
  // total ~47.5 MB

  k_fold<<<dim3(DM / 4), dim3(256), 0, stream>>>(pre_w, pre_b, q_filt, k_filt, Wt_hi, Wt_lo, bias64);
  k_q0v<<<dim3(MROWS / 128), dim3(512), 0, stream>>>(x, Wt_hi, Wt_lo, bias64, Q0V);
  k_chunksum<<<dim3(NCHUNK, BATCH), dim3(576), 0, stream>>>(Q0V, decay, S);
  k_scanchunks<<<dim3(BATCH), dim3(576), 0, stream>>>(S);
  k_scan_y<<<dim3(NCHUNK, BATCH), dim3(576), 0, stream>>>(Q0V, S, qp_w, qp_b, decay, Yb);
  k_owb<<<dim3((DM * KPAD + 255) / 256), dim3(256), 0, stream>>>(o_w, owb);  // after Q0V last use
  k_out_mfma<<<dim3((MROWS / 128) * (DM / 128)), dim3(256), 0, stream>>>(Yb, owb, o_b, out);
}

// Round 6
// 205.203 us; speedup vs baseline: 4.8086x; 1.3682x over previous
//
#include <hip/hip_runtime.h>
#include <hip/hip_bf16.h>
#include <math.h>

#define T_SEQ   2048
#define DM      1024
#define KF      32
#define BATCH   16
#define CPDIM   528
#define KPAD    576               // CPDIM padded to 9*64 for the final GEMM
#define MROWS   (BATCH * T_SEQ)   // 32768
#define NCHUNK  32
#define TCHUNK  64

typedef __bf16 bf16x8 __attribute__((ext_vector_type(8)));
typedef float f32x4 __attribute__((ext_vector_type(4)));
typedef unsigned uint2v __attribute__((ext_vector_type(2)));

// split v into bf16 hi (RNE) + bf16 lo (trunc of residual), packed (hi<<16)|lo
__device__ __forceinline__ unsigned packsplit(float v) {
  unsigned u = __float_as_uint(v);
  unsigned h = (u + 0x7fffu + ((u >> 16) & 1u)) & 0xffff0000u;
  float rr = v - __uint_as_float(h);
  return h | (__float_as_uint(rr) >> 16);
}

// RNE f32 -> bf16 (as u16)
__device__ __forceinline__ unsigned short f2bf(float f) {
  unsigned u = __float_as_uint(f);
  return (unsigned short)((u + 0x7fffu + ((u >> 16) & 1u)) >> 16);
}

// async global->LDS, 16 bytes per lane (dest = wave-uniform base + lane*16)
__device__ __forceinline__ void gload16(const void* g, void* l) {
  __builtin_amdgcn_global_load_lds(
      (const __attribute__((address_space(1))) unsigned*)g,
      (__attribute__((address_space(3))) unsigned*)l, 16, 0, 0);
}

// ---------------------------------------------------------------------------
// Kernel 1a: split-K fold partials. Grid (32 s-chunks, 16 i-tiles).
// Wp[sc][64 kfilter][1024 i] partial = sum over 64 s of F[s][k]*pre_w[s][i].
// ---------------------------------------------------------------------------
__global__ __launch_bounds__(256) void k_fold_part(const float* __restrict__ pre_w,
                                                   const float* __restrict__ qf,
                                                   const float* __restrict__ kfil,
                                                   float* __restrict__ Wp) {
  const int sc = blockIdx.x;   // 0..31
  const int it = blockIdx.y;   // 0..15
  const int s0 = sc * 64, i0 = it * 64;
  const int tid = threadIdx.x;
  __shared__ float fs[64][64];
  __shared__ float ps[64][64];
  for (int idx = tid; idx < 4096; idx += 256) {
    const int s = idx >> 6, c = idx & 63;
    fs[s][c] = (c < KF) ? qf[(s0 + s) * KF + c] : kfil[(s0 + s) * KF + c - KF];
    ps[s][c] = pre_w[(size_t)(s0 + s) * DM + i0 + c];
  }
  __syncthreads();
  const int i = tid & 63;      // lane-fast: coalesced/conflict-free on i
  const int kb = tid >> 6;     // filter block: kb*16..+15 (wave-uniform)
  float acc[16] = {};
  for (int s = 0; s < 64; ++s) {
    const float pv = ps[s][i];
    const float4 f0 = *reinterpret_cast<const float4*>(&fs[s][kb * 16 + 0]);
    const float4 f1 = *reinterpret_cast<const float4*>(&fs[s][kb * 16 + 4]);
    const float4 f2 = *reinterpret_cast<const float4*>(&fs[s][kb * 16 + 8]);
    const float4 f3 = *reinterpret_cast<const float4*>(&fs[s][kb * 16 + 12]);
    acc[0]  = fmaf(pv, f0.x, acc[0]);  acc[1]  = fmaf(pv, f0.y, acc[1]);
    acc[2]  = fmaf(pv, f0.z, acc[2]);  acc[3]  = fmaf(pv, f0.w, acc[3]);
    acc[4]  = fmaf(pv, f1.x, acc[4]);  acc[5]  = fmaf(pv, f1.y, acc[5]);
    acc[6]  = fmaf(pv, f1.z, acc[6]);  acc[7]  = fmaf(pv, f1.w, acc[7]);
    acc[8]  = fmaf(pv, f2.x, acc[8]);  acc[9]  = fmaf(pv, f2.y, acc[9]);
    acc[10] = fmaf(pv, f2.z, acc[10]); acc[11] = fmaf(pv, f2.w, acc[11]);
    acc[12] = fmaf(pv, f3.x, acc[12]); acc[13] = fmaf(pv, f3.y, acc[13]);
    acc[14] = fmaf(pv, f3.z, acc[14]); acc[15] = fmaf(pv, f3.w, acc[15]);
  }
#pragma unroll
  for (int j = 0; j < 16; ++j)
    Wp[((size_t)sc * 64 + kb * 16 + j) * DM + i0 + i] = acc[j];
}

// ---------------------------------------------------------------------------
// Kernel 1b: reduce 32 partials -> Wt hi/lo bf16 (layout [64 k][1024 i]).
// ---------------------------------------------------------------------------
__global__ __launch_bounds__(256) void k_foldred(const float* __restrict__ Wp,
                                                 unsigned short* __restrict__ Wt_hi,
                                                 unsigned short* __restrict__ Wt_lo) {
  const int idx = blockIdx.x * 256 + threadIdx.x;  // 0..65535 = k*1024+i
  float acc = 0.f;
#pragma unroll
  for (int sc = 0; sc < NCHUNK; ++sc)
    acc += Wp[(size_t)sc * 64 * DM + idx];
  const unsigned pk = packsplit(acc);
  Wt_hi[idx] = (unsigned short)(pk >> 16);
  Wt_lo[idx] = (unsigned short)(pk & 0xffffu);
}

// ---------------------------------------------------------------------------
// Kernel 1c: bias64[k] = sum_s pre_b[s] * F[s,k].
// ---------------------------------------------------------------------------
__global__ __launch_bounds__(256) void k_bias(const float* __restrict__ pre_b,
                                              const float* __restrict__ qf,
                                              const float* __restrict__ kfil,
                                              float* __restrict__ bias64) {
  __shared__ float part[4][64];
  const int k = threadIdx.x & 63;
  const int q = threadIdx.x >> 6;
  float acc = 0.f;
  for (int s = q * 512; s < (q + 1) * 512; ++s) {
    const float fv = (k < KF) ? qf[s * KF + k] : kfil[s * KF + k - KF];
    acc = fmaf(pre_b[s], fv, acc);
  }
  part[q][k] = acc;
  __syncthreads();
  if (threadIdx.x < 64)
    bias64[threadIdx.x] = part[0][k] + part[1][k] + part[2][k] + part[3][k];
}

// ---------------------------------------------------------------------------
// Kernel 2: Q0V = x @ Wt^T + bias64 via 3-term bf16 split MFMA.
// 64-row tiles -> 512 blocks x 4 waves. global_load_lds staging for x (f32)
// and Wt hi/lo; LDS linear, bank conflicts removed by pre-swizzled global
// source slots (X: slot^=row&7, W: slot^=(row>>1)&3). BK=32, 1 barrier/step.
// ---------------------------------------------------------------------------
__global__ __launch_bounds__(256) void k_q0v(const float* __restrict__ x,
                                             const unsigned short* __restrict__ Wt_hi,
                                             const unsigned short* __restrict__ Wt_lo,
                                             const float* __restrict__ bias64,
                                             float* __restrict__ Q0V) {
  __shared__ float Xs[2][64 * 32];            // 16 KB
  __shared__ unsigned short Wh[2][64 * 32];   // 8 KB
  __shared__ unsigned short Wl[2][64 * 32];   // 8 KB
  const int tid = threadIdx.x;
  const int m0 = blockIdx.x * 64;
  const int w = tid >> 6, l = tid & 63;
  const int g = l >> 4, r = l & 15;

  f32x4 acc[4] = {};

  auto stage = [&](int buf, int k0) {
#pragma unroll
    for (int q = 0; q < 2; ++q) {
      const int c = q * 256 + tid;
      const int row = c >> 3, sl = c & 7;
      const int col4 = (sl ^ (row & 7)) * 4;          // inverse swizzle on source
      gload16(&x[(size_t)(m0 + row) * DM + k0 + col4], &Xs[buf][c * 4]);
    }
    {
      const int row = tid >> 2, sl = tid & 3;
      const int colh = (sl ^ ((row >> 1) & 3)) * 8;
      gload16(&Wt_hi[(size_t)row * DM + k0 + colh], &Wh[buf][tid * 8]);
      gload16(&Wt_lo[(size_t)row * DM + k0 + colh], &Wl[buf][tid * 8]);
    }
  };

  stage(0, 0);
  for (int it = 0; it < DM / 32; ++it) {
    const int cur = it & 1;
    __syncthreads();   // implicit vmcnt(0)+lgkmcnt(0) drain -> buf[cur] ready
    if (it + 1 < DM / 32) stage(cur ^ 1, (it + 1) * 32);

    // A fragment: row w*16+r, k = g*8..g*8+7 (orig slots 2g, 2g+1)
    const int arow = w * 16 + r;
    const int sx = (2 * g) ^ (arow & 7);
    const int sy = (2 * g + 1) ^ (arow & 7);
    const f32x4 pX = *reinterpret_cast<const f32x4*>(&Xs[cur][arow * 32 + sx * 4]);
    const f32x4 pY = *reinterpret_cast<const f32x4*>(&Xs[cur][arow * 32 + sy * 4]);
    unsigned pk[8];
#pragma unroll
    for (int e = 0; e < 4; ++e) { pk[e] = packsplit(pX[e]); pk[4 + e] = packsplit(pY[e]); }
    union { unsigned u[4]; bf16x8 v; } ah, al;
#pragma unroll
    for (int j = 0; j < 4; ++j) {
      ah.u[j] = (pk[2 * j] >> 16) | (pk[2 * j + 1] & 0xffff0000u);
      al.u[j] = (pk[2 * j] & 0xffffu) | (pk[2 * j + 1] << 16);
    }

    bf16x8 bh[4], bl[4];
#pragma unroll
    for (int n = 0; n < 4; ++n) {
      const int brow = n * 16 + r;
      const int bs = g ^ ((brow >> 1) & 3);
      const int off = brow * 32 + bs * 8;
      bh[n] = *reinterpret_cast<const bf16x8*>(&Wh[cur][off]);
      bl[n] = *reinterpret_cast<const bf16x8*>(&Wl[cur][off]);
    }
#pragma unroll
    for (int n = 0; n < 4; ++n) {
      acc[n] = __builtin_amdgcn_mfma_f32_16x16x32_bf16(bh[n], ah.v, acc[n], 0, 0, 0);
      acc[n] = __builtin_amdgcn_mfma_f32_16x16x32_bf16(bh[n], al.v, acc[n], 0, 0, 0);
      acc[n] = __builtin_amdgcn_mfma_f32_16x16x32_bf16(bl[n], ah.v, acc[n], 0, 0, 0);
    }
  }
  // D: row-idx(g*4+j) <-> W side (Q0V col), col-idx(r) <-> x side (Q0V row)
  const int row_o = m0 + w * 16 + r;
#pragma unroll
  for (int n = 0; n < 4; ++n) {
    const int col_o = n * 16 + g * 4;
    const float4 bb = *reinterpret_cast<const float4*>(&bias64[col_o]);
    float4 v;
    v.x = acc[n][0] + bb.x; v.y = acc[n][1] + bb.y;
    v.z = acc[n][2] + bb.z; v.w = acc[n][3] + bb.w;
    *reinterpret_cast<float4*>(&Q0V[(size_t)row_o * 64 + col_o]) = v;
  }
}

// ---------------------------------------------------------------------------
// Kernel 3: per-chunk sums of Z.
// ---------------------------------------------------------------------------
__global__ __launch_bounds__(576) void k_chunksum(const float* __restrict__ Q0V,
                                                  const float* __restrict__ decay,
                                                  float* __restrict__ S) {
  const int ch = blockIdx.x;
  const int b  = blockIdx.y;
  __shared__ float vs[TCHUNK * KF];
  __shared__ float dec[TCHUNK];
  const int tid = threadIdx.x;
  const int t0 = ch * TCHUNK;

  for (int idx = tid; idx < TCHUNK * KF; idx += 576) {
    const int t = idx >> 5, j = idx & 31;
    vs[idx] = Q0V[(size_t)(b * T_SEQ + t0 + t) * 64 + KF + j];
  }
  if (tid < TCHUNK) dec[tid] = decay[t0 + tid];
  __syncthreads();

  if (tid >= CPDIM) return;
  const int c = tid;
  int i = 0, rem = c;
  while (rem >= KF - i) { rem -= KF - i; ++i; }
  const int j = i + rem;
  const float sc = (i == j) ? 1.0f : 1.41421356237309515f;
  float h = 0.f;
#pragma unroll 4
  for (int t = 0; t < TCHUNK; ++t)
    h = fmaf(vs[t * KF + i] * vs[t * KF + j], dec[t], h);
  S[(size_t)(b * NCHUNK + ch) * CPDIM + c] = h * sc;
}

// ---------------------------------------------------------------------------
// Kernel 4: exclusive scan of chunk sums (in place), register-batched loads.
// ---------------------------------------------------------------------------
__global__ __launch_bounds__(576) void k_scanchunks(float* __restrict__ S) {
  const int b = blockIdx.x;
  const int c = threadIdx.x;
  if (c >= CPDIM) return;
  float v[NCHUNK];
#pragma unroll
  for (int ch = 0; ch < NCHUNK; ++ch)
    v[ch] = S[(size_t)(b * NCHUNK + ch) * CPDIM + c];
  float run = 0.f;
#pragma unroll
  for (int ch = 0; ch < NCHUNK; ++ch) {
    S[(size_t)(b * NCHUNK + ch) * CPDIM + c] = run;
    run += v[ch];
  }
}

// ---------------------------------------------------------------------------
// Kernel 5: replay scan, expand Q, write Yb = bf16(Q*H), K-padded to 576.
// ---------------------------------------------------------------------------
__global__ __launch_bounds__(576) void k_scan_y(const float* __restrict__ Q0V,
                                                const float* __restrict__ S,
                                                const float* __restrict__ qp_w,
                                                const float* __restrict__ qp_b,
                                                const float* __restrict__ decay,
                                                unsigned short* __restrict__ Yb) {
  const int ch = blockIdx.x;
  const int b  = blockIdx.y;
  __shared__ float vs[TCHUNK * KF];
  __shared__ float qs[TCHUNK * KF];
  __shared__ float dec[TCHUNK];
  const int tid = threadIdx.x;
  const int t0 = ch * TCHUNK;

  for (int idx = tid; idx < TCHUNK * KF; idx += 576) {
    const int t = idx >> 5, j = idx & 31;
    const size_t row = (size_t)(b * T_SEQ + t0 + t) * 64;
    qs[idx] = Q0V[row + j];
    vs[idx] = Q0V[row + KF + j];
  }
  if (tid < TCHUNK) dec[tid] = decay[t0 + tid];
  __syncthreads();

  const int c = tid;
  if (c >= CPDIM) {
    for (int t = 0; t < TCHUNK; ++t)
      Yb[(size_t)(b * T_SEQ + t0 + t) * KPAD + c] = 0;
    return;
  }
  int i = 0, rem = c;
  while (rem >= KF - i) { rem -= KF - i; ++i; }
  const int j = i + rem;
  const float sc = (i == j) ? 1.0f : 1.41421356237309515f;

  float w[KF];
#pragma unroll
  for (int q = 0; q < KF; ++q) w[q] = qp_w[c * KF + q];
  const float qb = qp_b[c];

  float h = S[(size_t)(b * NCHUNK + ch) * CPDIM + c];
  for (int t = 0; t < TCHUNK; ++t) {
    const float z = vs[t * KF + i] * vs[t * KF + j] * sc * dec[t];
    h += z;
    float qv = qb;
#pragma unroll
    for (int q = 0; q < KF; ++q) qv = fmaf(w[q], qs[t * KF + q], qv);
    Yb[(size_t)(b * T_SEQ + t0 + t) * KPAD + c] = f2bf(qv * h);
  }
}

// ---------------------------------------------------------------------------
// Kernel 5b: o_w -> bf16, K-padded to 576.
// ---------------------------------------------------------------------------
__global__ __launch_bounds__(256) void k_owb(const float* __restrict__ ow,
                                             unsigned short* __restrict__ owb) {
  const int idx = blockIdx.x * 256 + threadIdx.x;
  if (idx >= DM * KPAD) return;
  const int n = idx / KPAD, k = idx - n * KPAD;
  owb[idx] = (k < CPDIM) ? f2bf(ow[(size_t)n * CPDIM + k]) : (unsigned short)0;
}

// ---------------------------------------------------------------------------
// Kernel 6: out = Y @ o_w^T + o_b, single bf16 MFMA (m97 structure).
// ---------------------------------------------------------------------------
__global__ __launch_bounds__(256) void k_out_mfma(const unsigned short* __restrict__ Yb,
                                                  const unsigned short* __restrict__ owb,
                                                  const float* __restrict__ ob,
                                                  float* __restrict__ out) {
  __shared__ unsigned short As[128 * 64];   // 16 KB
  __shared__ unsigned short Bs[128 * 64];   // 16 KB

  const int wg = blockIdx.x;
  const int nb = (wg & 7) * 256 + (wg >> 3);
  const int m0 = (nb >> 3) * 128;
  const int n0 = (nb & 7) * 128;

  const int tid = threadIdx.x;
  const int w = tid >> 6, l = tid & 63;
  const int wr = w >> 1, wc = w & 1;
  const int g = l >> 4, r = l & 15;

  f32x4 acc[4][4] = {};

  auto stage = [&](int k0) {
#pragma unroll
    for (int i = 0; i < 4; ++i) {
      const int c = i * 256 + tid;
      const int row = c >> 3, colh = (c & 7) * 8;
      gload16(&Yb [(size_t)(m0 + row) * KPAD + k0 + colh], &As[c * 8]);
      gload16(&owb[(size_t)(n0 + row) * KPAD + k0 + colh], &Bs[c * 8]);
    }
  };

  stage(0);
  for (int it = 0; it < KPAD / 64; ++it) {
    __syncthreads();

#pragma unroll
    for (int ksub = 0; ksub < 2; ++ksub) {
      bf16x8 af[4], bf[4];
      const int kh = ksub * 32 + g * 8;
#pragma unroll
      for (int m = 0; m < 4; ++m)
        af[m] = *reinterpret_cast<const bf16x8*>(&As[(wr * 64 + m * 16 + r) * 64 + kh]);
#pragma unroll
      for (int n = 0; n < 4; ++n)
        bf[n] = *reinterpret_cast<const bf16x8*>(&Bs[(wc * 64 + n * 16 + r) * 64 + kh]);
#pragma unroll
      for (int m = 0; m < 4; ++m)
#pragma unroll
        for (int n = 0; n < 4; ++n)
          acc[m][n] = __builtin_amdgcn_mfma_f32_16x16x32_bf16(bf[n], af[m], acc[m][n], 0, 0, 0);
    }

    __syncthreads();
    if (it + 1 < KPAD / 64) stage((it + 1) * 64);
  }

#pragma unroll
  for (int m = 0; m < 4; ++m) {
    const int row_o = m0 + wr * 64 + m * 16 + r;
#pragma unroll
    for (int n = 0; n < 4; ++n) {
      const int col_o = n0 + wc * 64 + n * 16 + g * 4;
      const float4 bb = *reinterpret_cast<const float4*>(&ob[col_o]);
      float4 v;
      v.x = acc[m][n][0] + bb.x; v.y = acc[m][n][1] + bb.y;
      v.z = acc[m][n][2] + bb.z; v.w = acc[m][n][3] + bb.w;
      *reinterpret_cast<float4*>(&out[(size_t)row_o * DM + col_o]) = v;
    }
  }
}

// ---------------------------------------------------------------------------
extern "C" void kernel_launch(void* const* d_in, const int* in_sizes, int n_in,
                              void* d_out, int out_size, void* d_ws, size_t ws_size,
                              hipStream_t stream) {
  const float* x      = (const float*)d_in[0];
  const float* pre_w  = (const float*)d_in[1];
  const float* pre_b  = (const float*)d_in[2];
  const float* q_filt = (const float*)d_in[3];
  const float* k_filt = (const float*)d_in[4];
  const float* qp_w   = (const float*)d_in[5];
  const float* qp_b   = (const float*)d_in[6];
  const float* o_w    = (const float*)d_in[7];
  const float* o_b    = (const float*)d_in[8];
  const float* decay  = (const float*)d_in[9];
  float* out = (float*)d_out;

  char* ws = (char*)d_ws;
  unsigned short* Wt_hi = (unsigned short*)(ws);            // 128 KB
  unsigned short* Wt_lo = (unsigned short*)(ws + 131072);   // 128 KB
  float*    bias64 = (float*)(ws + 262144);                 // 256 B
  float*    Q0V    = (float*)(ws + 262400);                 // 8.39 MB
  unsigned short* owb = (unsigned short*)(ws + 262400);     // 1.18 MB, ALIASES Q0V
                                                            // (written after Q0V dead)
  float*    S      = (float*)(ws + 8651008);                // 270 KB
  unsigned short* Yb = (unsigned short*)(ws + 9732352);     // 37.75 MB (ends 47.5 MB)
  float*    Wp     = (float*)(ws + 50331648);               // 8.39 MB (ends 58.7 MB)
  // total < 58.8 MB (prior rounds used 78.9 MB successfully)

  k_fold_part<<<dim3(NCHUNK, 16), dim3(256), 0, stream>>>(pre_w, q_filt, k_filt, Wp);
  k_foldred<<<dim3(256), dim3(256), 0, stream>>>(Wp, Wt_hi, Wt_lo);
  k_bias<<<dim3(1), dim3(256), 0, stream>>>(pre_b, q_filt, k_filt, bias64);
  k_q0v<<<dim3(MROWS / 64), dim3(256), 0, stream>>>(x, Wt_hi, Wt_lo, bias64, Q0V);
  k_chunksum<<<dim3(NCHUNK, BATCH), dim3(576), 0, stream>>>(Q0V, decay, S);
  k_scanchunks<<<dim3(BATCH), dim3(576), 0, stream>>>(S);
  k_scan_y<<<dim3(NCHUNK, BATCH), dim3(576), 0, stream>>>(Q0V, S, qp_w, qp_b, decay, Yb);
  k_owb<<<dim3((DM * KPAD + 255) / 256), dim3(256), 0, stream>>>(o_w, owb);  // after Q0V last use
  k_out_mfma<<<dim3((MROWS / 128) * (DM / 128)), dim3(256), 0, stream>>>(Yb, owb, o_b, out);
}